// Round 5
// baseline (395.217 us; speedup 1.0000x reference)
//
#include <hip/hip_runtime.h>
#include <hip/hip_bf16.h>
#include <math.h>

#define M_ROWS 32768
#define NE 2048
#define EDIM 128

// d_out element offsets (fp32)
#define O_LOSS 0
#define O_ZQ 1
#define O_PERP 4194305
#define O_MINENC 4194306
#define O_IDX 71303170ll

// ---------------- eq = ||e_n||^2, and zero the histogram ----------------
__global__ void eq_kernel(const float* __restrict__ emb, float* __restrict__ eq,
                          int* __restrict__ hist) {
    int n = blockIdx.x;            // 2048 blocks, 64 threads (1 wave)
    int lane = threadIdx.x;
    float v0 = emb[(size_t)n * EDIM + lane];
    float v1 = emb[(size_t)n * EDIM + 64 + lane];
    float s = v0 * v0 + v1 * v1;
    #pragma unroll
    for (int off = 32; off >= 1; off >>= 1) s += __shfl_down(s, off);
    if (lane == 0) { eq[n] = s; hist[n] = 0; }
}

// ---------------- argmin over n of (||z_m||^2 + eq[n]) - 2*z.e[n] ----------------
// fp32-quantized exactly like the reference (the +||z||^2 at ~128 scale quantizes d
// to ulp ~1.5e-5; emulating that is required for numpy-matching tie-breaks).
//
// Round-5 structure: 8x8 register micro-tile, block tile 128 rows x 128 e-cols,
// 256 threads (16 tr x 16 tc), grid = 256 blocks = exactly 1/CU.
// Per cc-chunk: 16 ds_read_b128 feed 256 FMAs -> LDS:VALU ~1:1 (was 2:1 at 4x4).
// LDS swizzle: 16B chunk cc of row r at physical chunk cc ^ ((r>>3)&7).
//  - za[r]: 4 tr per wave -> 4 distinct quads, 16-lane broadcast: conflict-free.
//  - eb[c]: rows tc*8+c -> key = tc&7 -> 8 quads x 2 addrs: 2-way (free, m136).
__global__ __launch_bounds__(256, 1) void argmin_kernel(const float* __restrict__ z,
                                                        const float* __restrict__ emb,
                                                        const float* __restrict__ eq,
                                                        int* __restrict__ out_idx) {
    __shared__ float zs[128 * 128];   // 64 KB, swizzled
    __shared__ float es[128 * 128];   // 64 KB, swizzled
    __shared__ float zsums[128];
    const int tid = threadIdx.x;
    const int m0 = blockIdx.x * 128;
    const int tr = tid >> 4;        // 0..15 row-group (8 rows each)
    const int tc = tid & 15;        // 0..15 col-group (8 cols each)

    // stage z tile (128x128 floats = 4096 float4), swizzled store
    for (int i = tid; i < 4096; i += 256) {
        int r = i >> 5, cc = i & 31;
        float4 v = reinterpret_cast<const float4*>(z + (size_t)(m0 + r) * EDIM)[cc];
        *reinterpret_cast<float4*>(&zs[r * 128 + ((cc ^ ((r >> 3) & 7)) << 2)]) = v;
    }
    __syncthreads();
    // per-row ||z||^2 in fp32, k-ascending order (bit-identical to scalar loop;
    // any fp32 zsum at this scale differs from the reference's by an exact multiple
    // of the rounding grid, which shifts all candidates identically)
    if (tid < 128) {
        const float* zr = &zs[tid * 128];
        const int key = (tid >> 3) & 7;
        float s = 0.0f;
        for (int cc = 0; cc < 32; cc++) {
            float4 v = *reinterpret_cast<const float4*>(zr + ((cc ^ key) << 2));
            s += v.x * v.x;
            s += v.y * v.y;
            s += v.z * v.z;
            s += v.w * v.w;
        }
        zsums[tid] = s;
    }
    __syncthreads();

    float zsum_r[8];
    #pragma unroll
    for (int r = 0; r < 8; r++) zsum_r[r] = zsums[tr * 8 + r];

    float best[8];
    int   bidx[8];
    #pragma unroll
    for (int r = 0; r < 8; r++) { best[r] = 3.4e38f; bidx[r] = 0; }

    const int keyz = tr & 7;        // storage key for rows tr*8..tr*8+7
    const int keye = tc & 7;        // storage key for rows tc*8..tc*8+7

    for (int t = 0; t < NE / 128; t++) {
        if (t > 0) __syncthreads();   // previous tile's readers done with es
        for (int i = tid; i < 4096; i += 256) {
            int r = i >> 5, cc = i & 31;
            float4 v = reinterpret_cast<const float4*>(emb + (size_t)(t * 128 + r) * EDIM)[cc];
            *reinterpret_cast<float4*>(&es[r * 128 + ((cc ^ ((r >> 3) & 7)) << 2)]) = v;
        }
        __syncthreads();

        float acc[8][8] = {};
        for (int cc = 0; cc < 32; cc++) {      // logical chunk cc = k/4, ascending
            const int oz = (cc ^ keyz) << 2;
            const int oe = (cc ^ keye) << 2;
            float4 za[8], eb[8];
            #pragma unroll
            for (int r = 0; r < 8; r++)
                za[r] = *reinterpret_cast<const float4*>(&zs[(tr * 8 + r) * 128 + oz]);
            #pragma unroll
            for (int c = 0; c < 8; c++)
                eb[c] = *reinterpret_cast<const float4*>(&es[(tc * 8 + c) * 128 + oe]);
            #pragma unroll
            for (int r = 0; r < 8; r++)
                #pragma unroll
                for (int c = 0; c < 8; c++)
                    acc[r][c] += za[r].x * eb[c].x + za[r].y * eb[c].y
                               + za[r].z * eb[c].z + za[r].w * eb[c].w;
        }

        #pragma unroll
        for (int c = 0; c < 8; c++) {       // increasing n order; strict < keeps earliest
            float eqv = eq[t * 128 + tc * 8 + c];
            int n = t * 128 + tc * 8 + c;
            #pragma unroll
            for (int r = 0; r < 8; r++) {
                float zse = zsum_r[r] + eqv;       // fp32 round at ~128 scale
                float val = zse - 2.0f * acc[r][c]; // 2*acc exact, single round
                if (val < best[r]) { best[r] = val; bidx[r] = n; }
            }
        }
    }

    // reduce across the 16 tc-threads (offs 8,4,2,1 stay within the 16-lane group)
    #pragma unroll
    for (int off = 8; off >= 1; off >>= 1) {
        #pragma unroll
        for (int r = 0; r < 8; r++) {
            float ov = __shfl_xor(best[r], off);
            int   oi = __shfl_xor(bidx[r], off);
            if (ov < best[r] || (ov == best[r] && oi < bidx[r])) {
                best[r] = ov; bidx[r] = oi;
            }
        }
    }
    if (tc == 0) {
        #pragma unroll
        for (int r = 0; r < 8; r++) out_idx[m0 + tr * 8 + r] = bidx[r];
    }
}

// ---------------- min_encodings one-hot fill (float2 stores; region is 8B-aligned) ----
__global__ __launch_bounds__(256) void minenc_kernel(const int* __restrict__ idx,
                                                     float* __restrict__ out /* d_out+O_MINENC */) {
    size_t i = (size_t)blockIdx.x * blockDim.x + threadIdx.x;
    const size_t total = (size_t)M_ROWS * (NE / 2);   // float2 count
    const size_t stride = (size_t)gridDim.x * blockDim.x;
    for (; i < total; i += stride) {
        int row = (int)(i >> 10);
        int col = (int)(i & 1023) << 1;
        int id = idx[row];
        float2 v;
        v.x = (col == id) ? 1.0f : 0.0f;
        v.y = (col + 1 == id) ? 1.0f : 0.0f;
        reinterpret_cast<float2*>(out)[i] = v;
    }
}

// ---------------- gather z_q, write z_q_st, idx(float), loss partials, histogram ----
__global__ __launch_bounds__(256) void gather_kernel(const float* __restrict__ z,
                                                     const float* __restrict__ emb,
                                                     const int* __restrict__ idx,
                                                     float* __restrict__ out,
                                                     float* __restrict__ partial,
                                                     int* __restrict__ hist) {
    __shared__ float red[256];
    const int tid = threadIdx.x;
    const int rl = tid >> 4;      // 16 rows per block
    const int sub = tid & 15;     // 16 threads per row, 8 elems each
    const int row = blockIdx.x * 16 + rl;
    const int id = idx[row];

    const float* zr = z + (size_t)row * EDIM + sub * 8;
    const float* er = emb + (size_t)id * EDIM + sub * 8;
    float* outr = out + O_ZQ + (size_t)row * EDIM + sub * 8;

    float4 z0 = reinterpret_cast<const float4*>(zr)[0];
    float4 z1 = reinterpret_cast<const float4*>(zr)[1];
    float4 e0 = reinterpret_cast<const float4*>(er)[0];
    float4 e1 = reinterpret_cast<const float4*>(er)[1];

    float zz[8] = {z0.x, z0.y, z0.z, z0.w, z1.x, z1.y, z1.z, z1.w};
    float ee[8] = {e0.x, e0.y, e0.z, e0.w, e1.x, e1.y, e1.z, e1.w};
    float s = 0.0f;
    #pragma unroll
    for (int j = 0; j < 8; j++) {
        float d = ee[j] - zz[j];
        outr[j] = zz[j] + d;      // match reference's z + (z_q - z) rounding
        s += d * d;
    }
    if (sub == 0) {
        atomicAdd(&hist[id], 1);
        out[O_IDX + row] = (float)id;
    }
    red[tid] = s;
    __syncthreads();
    #pragma unroll
    for (int o = 128; o >= 1; o >>= 1) {
        if (tid < o) red[tid] += red[tid + o];
        __syncthreads();
    }
    if (tid == 0) partial[blockIdx.x] = red[0];
}

// ---------------- finalize: loss + perplexity (deterministic fixed-order) ----------
__global__ __launch_bounds__(256) void finalize_kernel(const float* __restrict__ partial,
                                                       const int* __restrict__ hist,
                                                       float* __restrict__ out) {
    __shared__ float red[256];
    const int tid = threadIdx.x;
    float s = 0.0f;
    for (int i = 0; i < 8; i++) s += partial[tid * 8 + i];
    red[tid] = s;
    __syncthreads();
    #pragma unroll
    for (int o = 128; o >= 1; o >>= 1) {
        if (tid < o) red[tid] += red[tid + o];
        __syncthreads();
    }
    if (tid == 0) out[O_LOSS] = 1.25f * red[0] / (float)((size_t)M_ROWS * EDIM);
    __syncthreads();

    float h = 0.0f;
    for (int i = 0; i < 8; i++) {
        float p = (float)hist[tid * 8 + i] * (1.0f / (float)M_ROWS);
        h += p * logf(p + 1e-10f);
    }
    red[tid] = h;
    __syncthreads();
    #pragma unroll
    for (int o = 128; o >= 1; o >>= 1) {
        if (tid < o) red[tid] += red[tid + o];
        __syncthreads();
    }
    if (tid == 0) out[O_PERP] = expf(-red[0]);
}

extern "C" void kernel_launch(void* const* d_in, const int* in_sizes, int n_in,
                              void* d_out, int out_size, void* d_ws, size_t ws_size,
                              hipStream_t stream) {
    const float* z   = (const float*)d_in[0];
    const float* emb = (const float*)d_in[1];
    float* out = (float*)d_out;

    char* ws = (char*)d_ws;
    float* eq     = (float*)ws;                 // 2048 f32
    int*   idx    = (int*)(ws + 8192);          // 32768 i32
    int*   hist   = (int*)(ws + 8192 + 131072); // 2048 i32
    float* part   = (float*)(ws + 8192 + 131072 + 8192); // 2048 f32

    eq_kernel<<<NE, 64, 0, stream>>>(emb, eq, hist);
    argmin_kernel<<<M_ROWS / 128, 256, 0, stream>>>(z, emb, eq, idx);
    minenc_kernel<<<8192, 256, 0, stream>>>(idx, out + O_MINENC);
    gather_kernel<<<M_ROWS / 16, 256, 0, stream>>>(z, emb, idx, out, part, hist);
    finalize_kernel<<<1, 256, 0, stream>>>(part, hist, out);
}

// Round 6
// 274.663 us; speedup vs baseline: 1.4389x; 1.4389x over previous
//
#include <hip/hip_runtime.h>
#include <hip/hip_bf16.h>
#include <math.h>

#define M_ROWS 32768
#define NE 2048
#define EDIM 128

// d_out element offsets (fp32)
#define O_LOSS 0
#define O_ZQ 1
#define O_PERP 4194305
#define O_MINENC 4194306
#define O_IDX 71303170ll

// ---------------- eq = ||e_n||^2, and zero the histogram ----------------
__global__ void eq_kernel(const float* __restrict__ emb, float* __restrict__ eq,
                          int* __restrict__ hist) {
    int n = blockIdx.x;            // 2048 blocks, 64 threads (1 wave)
    int lane = threadIdx.x;
    float v0 = emb[(size_t)n * EDIM + lane];
    float v1 = emb[(size_t)n * EDIM + 64 + lane];
    float s = v0 * v0 + v1 * v1;
    #pragma unroll
    for (int off = 32; off >= 1; off >>= 1) s += __shfl_down(s, off);
    if (lane == 0) { eq[n] = s; hist[n] = 0; }
}

// ---------------- argmin over n of (||z_m||^2 + eq[n]) - 2*z.e[n] ----------------
// fp32-quantized exactly like the reference (the +||z||^2 at ~128 scale quantizes d
// to ulp ~1.5e-5; emulating that is required for numpy-matching tie-breaks).
//
// Round-6 structure (from the LDS-pipe model: ds_read_b128 ~12cyc on the per-CU
// LDS pipe was the round-4 bottleneck at 3x oversubscription):
//   512 threads = 8 waves (2/SIMD for latency hiding), block tile 128 rows x 256 n,
//   8x8 micro-tile -> per chunk per wave: 16 b128 reads feed 256 FMA-instr
//   (LDS:VALU = 1.5:1 vs 3:1 at 4x4). LDS: zs 64KB resident + es 64KB staged in
//   two k-halves per t-tile = 128.5KB, 1 block/CU.
//   Inner product: pure fmaf chains, k-ascending (4 VALU ops per 4 MACs).
// Swizzle: 16B chunk cc of row r at physical chunk cc ^ ((r>>3)&7).
//   za: key=tr&7 uniform per thread, 16 distinct addrs/wave, broadcast: free.
//   eb: key=tc&7 -> addresses spread across bank quads: ~2-way worst (free, m136).
__global__ __launch_bounds__(512, 1) void argmin_kernel(const float* __restrict__ z,
                                                        const float* __restrict__ emb,
                                                        const float* __restrict__ eq,
                                                        int* __restrict__ out_idx) {
    __shared__ float zs[128 * 128];   // 64 KB, swizzled, resident (full k)
    __shared__ float es[256 * 64];    // 64 KB, swizzled, one k-half of 256 e-rows
    __shared__ float zsums[128];
    const int tid = threadIdx.x;
    const int m0 = blockIdx.x * 128;
    const int tr = tid >> 5;        // 0..15 row-group (8 rows each)
    const int tc = tid & 31;        // 0..31 col-group (8 cols each)

    // stage z tile (128x128 floats = 4096 float4), swizzled store
    for (int i = tid; i < 4096; i += 512) {
        int r = i >> 5, cc = i & 31;
        float4 v = reinterpret_cast<const float4*>(z + (size_t)(m0 + r) * EDIM)[cc];
        *reinterpret_cast<float4*>(&zs[r * 128 + ((cc ^ ((r >> 3) & 7)) << 2)]) = v;
    }
    __syncthreads();
    // per-row ||z||^2 in fp32, k-ascending order (same form as passing rounds)
    if (tid < 128) {
        const float* zr = &zs[tid * 128];
        const int key = (tid >> 3) & 7;
        float s = 0.0f;
        for (int cc = 0; cc < 32; cc++) {
            float4 v = *reinterpret_cast<const float4*>(zr + ((cc ^ key) << 2));
            s += v.x * v.x;
            s += v.y * v.y;
            s += v.z * v.z;
            s += v.w * v.w;
        }
        zsums[tid] = s;
    }
    __syncthreads();

    float zsum_r[8];
    #pragma unroll
    for (int r = 0; r < 8; r++) zsum_r[r] = zsums[tr * 8 + r];

    float best[8];
    int   bidx[8];
    #pragma unroll
    for (int r = 0; r < 8; r++) { best[r] = 3.4e38f; bidx[r] = 0; }

    const int keyz = tr & 7;        // storage key for z rows tr*8..tr*8+7
    const int keye = tc & 7;        // storage key for e rows tc*8..tc*8+7

    for (int t = 0; t < NE / 256; t++) {       // 8 t-tiles of 256 e-rows
        float acc[8][8] = {};

        #pragma unroll
        for (int h = 0; h < 2; h++) {          // two k-halves: k in [h*64, h*64+64)
            // stage es: 256 e-rows x 64 k = 4096 float4, swizzled (cc local 0..15)
            for (int i = tid; i < 4096; i += 512) {
                int r = i >> 4, cc = i & 15;
                float4 v = reinterpret_cast<const float4*>(
                    emb + (size_t)(t * 256 + r) * EDIM + h * 64)[cc];
                *reinterpret_cast<float4*>(&es[r * 64 + ((cc ^ ((r >> 3) & 7)) << 2)]) = v;
            }
            __syncthreads();

            for (int cl = 0; cl < 16; cl++) {  // local chunk; global chunk = h*16+cl
                const int cc = h * 16 + cl;    // ascending k across halves
                const int oz = (cc ^ keyz) << 2;
                const int oe = ((cl ^ keye) & 15) << 2;
                float4 za[8], eb[8];
                #pragma unroll
                for (int r = 0; r < 8; r++)
                    za[r] = *reinterpret_cast<const float4*>(&zs[(tr * 8 + r) * 128 + oz]);
                #pragma unroll
                for (int c = 0; c < 8; c++)
                    eb[c] = *reinterpret_cast<const float4*>(&es[(tc * 8 + c) * 64 + oe]);
                #pragma unroll
                for (int r = 0; r < 8; r++)
                    #pragma unroll
                    for (int c = 0; c < 8; c++)
                        acc[r][c] = fmaf(za[r].w, eb[c].w,
                                    fmaf(za[r].z, eb[c].z,
                                    fmaf(za[r].y, eb[c].y,
                                    fmaf(za[r].x, eb[c].x, acc[r][c]))));
            }
            __syncthreads();                   // readers done before next stage
        }

        #pragma unroll
        for (int c = 0; c < 8; c++) {          // increasing n; strict < keeps earliest
            int n = t * 256 + tc * 8 + c;
            float eqv = eq[n];
            #pragma unroll
            for (int r = 0; r < 8; r++) {
                float zse = zsum_r[r] + eqv;        // fp32 round at ~128 scale
                float val = zse - 2.0f * acc[r][c]; // 2*acc exact, single round
                if (val < best[r]) { best[r] = val; bidx[r] = n; }
            }
        }
    }

    // reduce across the 32 tc-threads (offsets 16..1 stay within each 32-lane half)
    #pragma unroll
    for (int off = 16; off >= 1; off >>= 1) {
        #pragma unroll
        for (int r = 0; r < 8; r++) {
            float ov = __shfl_xor(best[r], off);
            int   oi = __shfl_xor(bidx[r], off);
            if (ov < best[r] || (ov == best[r] && oi < bidx[r])) {
                best[r] = ov; bidx[r] = oi;
            }
        }
    }
    if (tc == 0) {
        #pragma unroll
        for (int r = 0; r < 8; r++) out_idx[m0 + tr * 8 + r] = bidx[r];
    }
}

// ---------------- min_encodings one-hot fill (float2 stores; region is 8B-aligned) ----
__global__ __launch_bounds__(256) void minenc_kernel(const int* __restrict__ idx,
                                                     float* __restrict__ out /* d_out+O_MINENC */) {
    size_t i = (size_t)blockIdx.x * blockDim.x + threadIdx.x;
    const size_t total = (size_t)M_ROWS * (NE / 2);   // float2 count
    const size_t stride = (size_t)gridDim.x * blockDim.x;
    for (; i < total; i += stride) {
        int row = (int)(i >> 10);
        int col = (int)(i & 1023) << 1;
        int id = idx[row];
        float2 v;
        v.x = (col == id) ? 1.0f : 0.0f;
        v.y = (col + 1 == id) ? 1.0f : 0.0f;
        reinterpret_cast<float2*>(out)[i] = v;
    }
}

// ---------------- gather z_q, write z_q_st, idx(float), loss partials, histogram ----
__global__ __launch_bounds__(256) void gather_kernel(const float* __restrict__ z,
                                                     const float* __restrict__ emb,
                                                     const int* __restrict__ idx,
                                                     float* __restrict__ out,
                                                     float* __restrict__ partial,
                                                     int* __restrict__ hist) {
    __shared__ float red[256];
    const int tid = threadIdx.x;
    const int rl = tid >> 4;      // 16 rows per block
    const int sub = tid & 15;     // 16 threads per row, 8 elems each
    const int row = blockIdx.x * 16 + rl;
    const int id = idx[row];

    const float* zr = z + (size_t)row * EDIM + sub * 8;
    const float* er = emb + (size_t)id * EDIM + sub * 8;
    float* outr = out + O_ZQ + (size_t)row * EDIM + sub * 8;

    float4 z0 = reinterpret_cast<const float4*>(zr)[0];
    float4 z1 = reinterpret_cast<const float4*>(zr)[1];
    float4 e0 = reinterpret_cast<const float4*>(er)[0];
    float4 e1 = reinterpret_cast<const float4*>(er)[1];

    float zz[8] = {z0.x, z0.y, z0.z, z0.w, z1.x, z1.y, z1.z, z1.w};
    float ee[8] = {e0.x, e0.y, e0.z, e0.w, e1.x, e1.y, e1.z, e1.w};
    float s = 0.0f;
    #pragma unroll
    for (int j = 0; j < 8; j++) {
        float d = ee[j] - zz[j];
        outr[j] = zz[j] + d;      // match reference's z + (z_q - z) rounding
        s += d * d;
    }
    if (sub == 0) {
        atomicAdd(&hist[id], 1);
        out[O_IDX + row] = (float)id;
    }
    red[tid] = s;
    __syncthreads();
    #pragma unroll
    for (int o = 128; o >= 1; o >>= 1) {
        if (tid < o) red[tid] += red[tid + o];
        __syncthreads();
    }
    if (tid == 0) partial[blockIdx.x] = red[0];
}

// ---------------- finalize: loss + perplexity (deterministic fixed-order) ----------
__global__ __launch_bounds__(256) void finalize_kernel(const float* __restrict__ partial,
                                                       const int* __restrict__ hist,
                                                       float* __restrict__ out) {
    __shared__ float red[256];
    const int tid = threadIdx.x;
    float s = 0.0f;
    for (int i = 0; i < 8; i++) s += partial[tid * 8 + i];
    red[tid] = s;
    __syncthreads();
    #pragma unroll
    for (int o = 128; o >= 1; o >>= 1) {
        if (tid < o) red[tid] += red[tid + o];
        __syncthreads();
    }
    if (tid == 0) out[O_LOSS] = 1.25f * red[0] / (float)((size_t)M_ROWS * EDIM);
    __syncthreads();

    float h = 0.0f;
    for (int i = 0; i < 8; i++) {
        float p = (float)hist[tid * 8 + i] * (1.0f / (float)M_ROWS);
        h += p * logf(p + 1e-10f);
    }
    red[tid] = h;
    __syncthreads();
    #pragma unroll
    for (int o = 128; o >= 1; o >>= 1) {
        if (tid < o) red[tid] += red[tid + o];
        __syncthreads();
    }
    if (tid == 0) out[O_PERP] = expf(-red[0]);
}

extern "C" void kernel_launch(void* const* d_in, const int* in_sizes, int n_in,
                              void* d_out, int out_size, void* d_ws, size_t ws_size,
                              hipStream_t stream) {
    const float* z   = (const float*)d_in[0];
    const float* emb = (const float*)d_in[1];
    float* out = (float*)d_out;

    char* ws = (char*)d_ws;
    float* eq     = (float*)ws;                 // 2048 f32
    int*   idx    = (int*)(ws + 8192);          // 32768 i32
    int*   hist   = (int*)(ws + 8192 + 131072); // 2048 i32
    float* part   = (float*)(ws + 8192 + 131072 + 8192); // 2048 f32

    eq_kernel<<<NE, 64, 0, stream>>>(emb, eq, hist);
    argmin_kernel<<<M_ROWS / 128, 512, 0, stream>>>(z, emb, eq, idx);
    minenc_kernel<<<8192, 256, 0, stream>>>(idx, out + O_MINENC);
    gather_kernel<<<M_ROWS / 16, 256, 0, stream>>>(z, emb, idx, out, part, hist);
    finalize_kernel<<<1, 256, 0, stream>>>(part, hist, out);
}

// Round 7
// 274.598 us; speedup vs baseline: 1.4393x; 1.0002x over previous
//
#include <hip/hip_runtime.h>
#include <hip/hip_bf16.h>
#include <math.h>

#define M_ROWS 32768
#define NE 2048
#define EDIM 128

// d_out element offsets (fp32)
#define O_LOSS 0
#define O_ZQ 1
#define O_PERP 4194305
#define O_MINENC 4194306
#define O_IDX 71303170ll

#define AS1 __attribute__((address_space(1)))
#define AS3 __attribute__((address_space(3)))

// async global->LDS DMA, 16B per lane. LDS dest is WAVE-UNIFORM base + lane*16
// (linear); the XOR swizzle is applied to the per-lane GLOBAL source address
// instead (m173 pattern), with the same involution applied at read time.
__device__ __forceinline__ void gload16(const float* g, float* l) {
    __builtin_amdgcn_global_load_lds((const AS1 void*)g, (AS3 void*)l, 16, 0, 0);
}

// ---------------- eq = ||e_n||^2, and zero the histogram ----------------
__global__ void eq_kernel(const float* __restrict__ emb, float* __restrict__ eq,
                          int* __restrict__ hist) {
    int n = blockIdx.x;            // 2048 blocks, 64 threads (1 wave)
    int lane = threadIdx.x;
    float v0 = emb[(size_t)n * EDIM + lane];
    float v1 = emb[(size_t)n * EDIM + 64 + lane];
    float s = v0 * v0 + v1 * v1;
    #pragma unroll
    for (int off = 32; off >= 1; off >>= 1) s += __shfl_down(s, off);
    if (lane == 0) { eq[n] = s; hist[n] = 0; }
}

// ---------------- argmin over n of (||z_m||^2 + eq[n]) - 2*z.e[n] ----------------
// fp32-quantized exactly like the reference (the +||z||^2 at ~128 scale quantizes d
// to ulp ~1.5e-5; emulating that is required for numpy-matching tie-breaks).
//
// Round-7: same math/shape as round 6 (512 thr = 8 waves, 128 rows x 256 n per
// sweep, 8x8 micro-tile, k-ascending fmaf chains) but staging via async
// global_load_lds (width 16) with ping-pong k-quarter es buffers:
//   quarter q: { issue DMA for q+1 -> buf^1 ; compute 8 chunks from buf ; barrier }
// __syncthreads drains vmcnt, so the issued loads land exactly at the barrier and
// their latency hides under ~2048 fmaf-instr of compute. No ds_write staging, no
// staging VGPRs.
// LDS: zs 64KB (full k, resident) + es 2 x 32KB (256 rows x 32 k each) = 128.5KB.
// Swizzle (both sides, same involution): 16B chunk cl of row r stored at physical
// chunk cl ^ ((r>>3)&7) -- applied by permuting the DMA *source* k-offset.
__global__ __launch_bounds__(512, 1) void argmin_kernel(const float* __restrict__ z,
                                                        const float* __restrict__ emb,
                                                        const float* __restrict__ eq,
                                                        int* __restrict__ out_idx) {
    __shared__ float zs[128 * 128];      // 64 KB, linear store, swizzled source
    __shared__ float es[2 * 256 * 32];   // 2 x 32 KB ping-pong
    __shared__ float zsums[128];
    const int tid = threadIdx.x;
    const int m0 = blockIdx.x * 128;
    const int tr = tid >> 5;        // 0..15 row-group (8 rows each)
    const int tc = tid & 31;        // 0..31 col-group (8 cols each)
    const int w  = tid >> 6;        // wave 0..7
    const int l  = tid & 63;        // lane

    // ---- prologue: DMA zs (full 128x128) and es quarter 0 ----
    #pragma unroll
    for (int j = 0; j < 8; j++) {
        const int idx = w * 512 + j * 64 + l;    // 16B-unit index in zs
        const int row = idx >> 5;                // 32 chunks per 128-float row
        const int cl  = (idx & 31) ^ ((row >> 3) & 7);   // XOR affects low 3 bits
        gload16(z + (size_t)(m0 + row) * EDIM + cl * 4,
                zs + w * 2048 + j * 256);        // floats: w*8KB + j*1KB
    }
    #pragma unroll
    for (int j = 0; j < 4; j++) {
        const int idx = w * 256 + j * 64 + l;    // 16B-unit index in es buf0
        const int row = idx >> 3;                // 8 chunks per 32-float row
        const int cl  = (idx & 7) ^ ((row >> 3) & 7);
        gload16(emb + (size_t)row * EDIM + 0 * 32 + cl * 4,
                es + w * 1024 + j * 256);        // floats: w*4KB + j*1KB
    }
    __syncthreads();                 // drains vmcnt: zs + es q0 landed

    // per-row ||z||^2 in fp32, k-ascending order (same form as passing rounds)
    if (tid < 128) {
        const float* zr = &zs[tid * 128];
        const int key = (tid >> 3) & 7;
        float s = 0.0f;
        for (int cc = 0; cc < 32; cc++) {
            float4 v = *reinterpret_cast<const float4*>(zr + ((cc ^ key) << 2));
            s += v.x * v.x;
            s += v.y * v.y;
            s += v.z * v.z;
            s += v.w * v.w;
        }
        zsums[tid] = s;
    }
    __syncthreads();

    float zsum_r[8];
    #pragma unroll
    for (int r = 0; r < 8; r++) zsum_r[r] = zsums[tr * 8 + r];

    float best[8];
    int   bidx[8];
    #pragma unroll
    for (int r = 0; r < 8; r++) { best[r] = 3.4e38f; bidx[r] = 0; }

    const int keyz = tr & 7;        // read key for z rows tr*8..tr*8+7
    const int keye = tc & 7;        // read key for e rows tc*8..tc*8+7

    int cur = 0;
    for (int t = 0; t < 8; t++) {              // 8 t-tiles of 256 e-rows
        float acc[8][8] = {};

        for (int q = 0; q < 4; q++) {          // 4 k-quarters (8 chunks each)
            const int gq = t * 4 + q;
            if (gq + 1 < 32) {                 // issue DMA for next quarter
                const int ng  = gq + 1;
                const int nt0 = (ng >> 2) * 256;
                const int nqk = (ng & 3) * 32;
                #pragma unroll
                for (int j = 0; j < 4; j++) {
                    const int idx = w * 256 + j * 64 + l;
                    const int row = idx >> 3;
                    const int cl  = (idx & 7) ^ ((row >> 3) & 7);
                    gload16(emb + (size_t)(nt0 + row) * EDIM + nqk + cl * 4,
                            es + (cur ^ 1) * 8192 + w * 1024 + j * 256);
                }
            }

            const float* esb = es + cur * 8192;
            for (int cl = 0; cl < 8; cl++) {   // global chunk cc = q*8+cl, ascending
                const int cc = q * 8 + cl;
                const int oz = (cc ^ keyz) << 2;
                const int oe = (cl ^ keye) << 2;
                float4 za[8], eb[8];
                #pragma unroll
                for (int r = 0; r < 8; r++)
                    za[r] = *reinterpret_cast<const float4*>(&zs[(tr * 8 + r) * 128 + oz]);
                #pragma unroll
                for (int c = 0; c < 8; c++)
                    eb[c] = *reinterpret_cast<const float4*>(&esb[(tc * 8 + c) * 32 + oe]);
                #pragma unroll
                for (int r = 0; r < 8; r++)
                    #pragma unroll
                    for (int c = 0; c < 8; c++)
                        acc[r][c] = fmaf(za[r].w, eb[c].w,
                                    fmaf(za[r].z, eb[c].z,
                                    fmaf(za[r].y, eb[c].y,
                                    fmaf(za[r].x, eb[c].x, acc[r][c]))));
            }
            __syncthreads();                   // readers done + next-quarter DMA landed
            cur ^= 1;
        }

        #pragma unroll
        for (int c = 0; c < 8; c++) {          // increasing n; strict < keeps earliest
            int n = t * 256 + tc * 8 + c;
            float eqv = eq[n];
            #pragma unroll
            for (int r = 0; r < 8; r++) {
                float zse = zsum_r[r] + eqv;        // fp32 round at ~128 scale
                float val = zse - 2.0f * acc[r][c]; // 2*acc exact, single round
                if (val < best[r]) { best[r] = val; bidx[r] = n; }
            }
        }
    }

    // reduce across the 32 tc-threads (offsets 16..1 stay within each 32-lane half)
    #pragma unroll
    for (int off = 16; off >= 1; off >>= 1) {
        #pragma unroll
        for (int r = 0; r < 8; r++) {
            float ov = __shfl_xor(best[r], off);
            int   oi = __shfl_xor(bidx[r], off);
            if (ov < best[r] || (ov == best[r] && oi < bidx[r])) {
                best[r] = ov; bidx[r] = oi;
            }
        }
    }
    if (tc == 0) {
        #pragma unroll
        for (int r = 0; r < 8; r++) out_idx[m0 + tr * 8 + r] = bidx[r];
    }
}

// ---------------- min_encodings one-hot fill (float2 stores; region is 8B-aligned) ----
__global__ __launch_bounds__(256) void minenc_kernel(const int* __restrict__ idx,
                                                     float* __restrict__ out /* d_out+O_MINENC */) {
    size_t i = (size_t)blockIdx.x * blockDim.x + threadIdx.x;
    const size_t total = (size_t)M_ROWS * (NE / 2);   // float2 count
    const size_t stride = (size_t)gridDim.x * blockDim.x;
    for (; i < total; i += stride) {
        int row = (int)(i >> 10);
        int col = (int)(i & 1023) << 1;
        int id = idx[row];
        float2 v;
        v.x = (col == id) ? 1.0f : 0.0f;
        v.y = (col + 1 == id) ? 1.0f : 0.0f;
        reinterpret_cast<float2*>(out)[i] = v;
    }
}

// ---------------- gather z_q, write z_q_st, idx(float), loss partials, histogram ----
__global__ __launch_bounds__(256) void gather_kernel(const float* __restrict__ z,
                                                     const float* __restrict__ emb,
                                                     const int* __restrict__ idx,
                                                     float* __restrict__ out,
                                                     float* __restrict__ partial,
                                                     int* __restrict__ hist) {
    __shared__ float red[256];
    const int tid = threadIdx.x;
    const int rl = tid >> 4;      // 16 rows per block
    const int sub = tid & 15;     // 16 threads per row, 8 elems each
    const int row = blockIdx.x * 16 + rl;
    const int id = idx[row];

    const float* zr = z + (size_t)row * EDIM + sub * 8;
    const float* er = emb + (size_t)id * EDIM + sub * 8;
    float* outr = out + O_ZQ + (size_t)row * EDIM + sub * 8;

    float4 z0 = reinterpret_cast<const float4*>(zr)[0];
    float4 z1 = reinterpret_cast<const float4*>(zr)[1];
    float4 e0 = reinterpret_cast<const float4*>(er)[0];
    float4 e1 = reinterpret_cast<const float4*>(er)[1];

    float zz[8] = {z0.x, z0.y, z0.z, z0.w, z1.x, z1.y, z1.z, z1.w};
    float ee[8] = {e0.x, e0.y, e0.z, e0.w, e1.x, e1.y, e1.z, e1.w};
    float s = 0.0f;
    #pragma unroll
    for (int j = 0; j < 8; j++) {
        float d = ee[j] - zz[j];
        outr[j] = zz[j] + d;      // match reference's z + (z_q - z) rounding
        s += d * d;
    }
    if (sub == 0) {
        atomicAdd(&hist[id], 1);
        out[O_IDX + row] = (float)id;
    }
    red[tid] = s;
    __syncthreads();
    #pragma unroll
    for (int o = 128; o >= 1; o >>= 1) {
        if (tid < o) red[tid] += red[tid + o];
        __syncthreads();
    }
    if (tid == 0) partial[blockIdx.x] = red[0];
}

// ---------------- finalize: loss + perplexity (deterministic fixed-order) ----------
__global__ __launch_bounds__(256) void finalize_kernel(const float* __restrict__ partial,
                                                       const int* __restrict__ hist,
                                                       float* __restrict__ out) {
    __shared__ float red[256];
    const int tid = threadIdx.x;
    float s = 0.0f;
    for (int i = 0; i < 8; i++) s += partial[tid * 8 + i];
    red[tid] = s;
    __syncthreads();
    #pragma unroll
    for (int o = 128; o >= 1; o >>= 1) {
        if (tid < o) red[tid] += red[tid + o];
        __syncthreads();
    }
    if (tid == 0) out[O_LOSS] = 1.25f * red[0] / (float)((size_t)M_ROWS * EDIM);
    __syncthreads();

    float h = 0.0f;
    for (int i = 0; i < 8; i++) {
        float p = (float)hist[tid * 8 + i] * (1.0f / (float)M_ROWS);
        h += p * logf(p + 1e-10f);
    }
    red[tid] = h;
    __syncthreads();
    #pragma unroll
    for (int o = 128; o >= 1; o >>= 1) {
        if (tid < o) red[tid] += red[tid + o];
        __syncthreads();
    }
    if (tid == 0) out[O_PERP] = expf(-red[0]);
}

extern "C" void kernel_launch(void* const* d_in, const int* in_sizes, int n_in,
                              void* d_out, int out_size, void* d_ws, size_t ws_size,
                              hipStream_t stream) {
    const float* z   = (const float*)d_in[0];
    const float* emb = (const float*)d_in[1];
    float* out = (float*)d_out;

    char* ws = (char*)d_ws;
    float* eq     = (float*)ws;                 // 2048 f32
    int*   idx    = (int*)(ws + 8192);          // 32768 i32
    int*   hist   = (int*)(ws + 8192 + 131072); // 2048 i32
    float* part   = (float*)(ws + 8192 + 131072 + 8192); // 2048 f32

    eq_kernel<<<NE, 64, 0, stream>>>(emb, eq, hist);
    argmin_kernel<<<M_ROWS / 128, 512, 0, stream>>>(z, emb, eq, idx);
    minenc_kernel<<<8192, 256, 0, stream>>>(idx, out + O_MINENC);
    gather_kernel<<<M_ROWS / 16, 256, 0, stream>>>(z, emb, idx, out, part, hist);
    finalize_kernel<<<1, 256, 0, stream>>>(part, hist, out);
}

// Round 8
// 215.010 us; speedup vs baseline: 1.8381x; 1.2771x over previous
//
#include <hip/hip_runtime.h>
#include <hip/hip_bf16.h>
#include <math.h>

#define M_ROWS 32768
#define NE 2048
#define EDIM 128

// d_out element offsets (fp32)
#define O_LOSS 0
#define O_ZQ 1
#define O_PERP 4194305
#define O_MINENC 4194306
#define O_IDX 71303170ll

#define AS1 __attribute__((address_space(1)))
#define AS3 __attribute__((address_space(3)))

typedef unsigned short u16;
typedef __attribute__((ext_vector_type(8))) short short8;   // 8 bf16 (4 VGPRs)
typedef __attribute__((ext_vector_type(16))) float f32x16;  // 32x32 MFMA acc

#define ZPLANE 4194304   // 32768*128
#define EPLANE 262144    // 2048*128

__device__ __forceinline__ u16 bf16_rne(float f) {          // round-to-nearest-even
    unsigned u = __float_as_uint(f);
    unsigned r = (u + 0x7FFFu + ((u >> 16) & 1u)) >> 16;
    return (u16)r;
}

// async global->LDS DMA, 16B/lane; LDS dest = wave-uniform base + lane*16.
__device__ __forceinline__ void gload16u(const u16* g, u16* l) {
    __builtin_amdgcn_global_load_lds((const AS1 void*)g, (AS3 void*)l, 16, 0, 0);
}

// ---------------- prep: 3-level bf16 split of z and emb ----------------
// z = zh + zm + zl with each level bf16 (exact-in-fp32 residual subtracts).
// Planes: z3[lv][32768*128], e3[lv][2048*128], row-major bf16.
__global__ __launch_bounds__(256) void prep_kernel(const float* __restrict__ z,
                                                   const float* __restrict__ emb,
                                                   u16* __restrict__ z3,
                                                   u16* __restrict__ e3) {
    const int ZQ = 1048576, EQ = 65536;            // float4 group counts
    int i = blockIdx.x * 256 + threadIdx.x;        // grid covers ZQ+EQ exactly
    if (i >= ZQ + EQ) return;
    const float4 v = (i < ZQ) ? reinterpret_cast<const float4*>(z)[i]
                              : reinterpret_cast<const float4*>(emb)[i - ZQ];
    float fv[4] = {v.x, v.y, v.z, v.w};
    u16 hs[4], ms[4], ls[4];
    #pragma unroll
    for (int j = 0; j < 4; j++) {
        u16 hb = bf16_rne(fv[j]);
        float fh = __uint_as_float((unsigned)hb << 16);
        float r1 = fv[j] - fh;                     // exact (Sterbenz)
        u16 mb = bf16_rne(r1);
        float fm = __uint_as_float((unsigned)mb << 16);
        float r2 = r1 - fm;                        // exact
        u16 lb = bf16_rne(r2);
        hs[j] = hb; ms[j] = mb; ls[j] = lb;
    }
    u16* base = (i < ZQ) ? z3 : e3;
    size_t PL = (i < ZQ) ? (size_t)ZPLANE : (size_t)EPLANE;
    size_t off = (size_t)((i < ZQ) ? i : (i - ZQ)) * 4;
    reinterpret_cast<ushort4*>(base + off)[0]          = make_ushort4(hs[0], hs[1], hs[2], hs[3]);
    reinterpret_cast<ushort4*>(base + PL + off)[0]     = make_ushort4(ms[0], ms[1], ms[2], ms[3]);
    reinterpret_cast<ushort4*>(base + 2 * PL + off)[0] = make_ushort4(ls[0], ls[1], ls[2], ls[3]);
}

// ---------------- zsums: per-row ||z||^2, bitwise identical to rounds 5-7 ----------
__global__ __launch_bounds__(256) void zsum_kernel(const float* __restrict__ z,
                                                   float* __restrict__ zsums) {
    __shared__ float zsh[128 * 128];
    const int tid = threadIdx.x;
    const int m0 = blockIdx.x * 128;
    for (int i = tid; i < 4096; i += 256) {
        int r = i >> 5, cc = i & 31;
        float4 v = reinterpret_cast<const float4*>(z + (size_t)(m0 + r) * EDIM)[cc];
        *reinterpret_cast<float4*>(&zsh[r * 128 + ((cc ^ ((r >> 3) & 7)) << 2)]) = v;
    }
    __syncthreads();
    if (tid < 128) {
        const float* zr = &zsh[tid * 128];
        const int key = (tid >> 3) & 7;
        float s = 0.0f;
        for (int cc = 0; cc < 32; cc++) {          // k-ascending (proven order)
            float4 v = *reinterpret_cast<const float4*>(zr + ((cc ^ key) << 2));
            s += v.x * v.x;
            s += v.y * v.y;
            s += v.z * v.z;
            s += v.w * v.w;
        }
        zsums[m0 + tid] = s;
    }
}

// ---------------- eq = ||e_n||^2, and zero the histogram (proven) ----------------
__global__ void eq_kernel(const float* __restrict__ emb, float* __restrict__ eq,
                          int* __restrict__ hist) {
    int n = blockIdx.x;
    int lane = threadIdx.x;
    float v0 = emb[(size_t)n * EDIM + lane];
    float v1 = emb[(size_t)n * EDIM + 64 + lane];
    float s = v0 * v0 + v1 * v1;
    #pragma unroll
    for (int off = 32; off >= 1; off >>= 1) s += __shfl_down(s, off);
    if (lane == 0) { eq[n] = s; hist[n] = 0; }
}

// ---------------- MFMA argmin: 6-term bf16 split, 32x32x16 ----------------
// val = fl(fl(zsum+eq) - 2*fl(acc_m+acc_c)); acc_m = dot(zh,eh) (dominant chain,
// rounding class == any fp32 dot == proven), acc_c = the 5 small cross-level terms
// (partials ~1e-4 -> negligible rounding). Products are exact in fp32.
// 512 thr = 8 waves (wm=w>>2 in {0,1} row-halves, wn=w&3 col-quarters).
// Per wave: AM=2 (64 rows), AN=1 (32 cols); t-tile = 128 cols; 16 t-tiles.
// zs: [lv][16 chunks][128 rows][8k] bf16 chunk-major (A-read: 32 consecutive rows
// x 16B = 512B span = conflict-free). es ping-pong: [2][lv][2 ch][128 cols][8k].
__global__ __launch_bounds__(512, 2) void argmin_mfma_kernel(
    const u16* __restrict__ z3, const u16* __restrict__ e3,
    const float* __restrict__ zsums, const float* __restrict__ eq,
    int* __restrict__ out_idx)
{
    __shared__ __align__(16) u16 zs[49152];     // 96 KB
    __shared__ __align__(16) u16 es[12288];     // 2 x 12 KB ping-pong
    __shared__ float zsl[128];
    __shared__ float cand_v[128 * 4];
    __shared__ int   cand_i[128 * 4];

    const int tid = threadIdx.x;
    const int w = tid >> 6, l = tid & 63;
    const int wm = w >> 2, wn = w & 3;
    const int h = l >> 5, r32 = l & 31;
    const int m0 = blockIdx.x * 128;

    // prologue: DMA zs (all 3 levels, full K) -- 12 instr/thread
    #pragma unroll
    for (int i = 0; i < 12; i++) {
        int s0 = i * 512 + w * 64;
        int s = s0 + l;
        int lv = s >> 11, ch = (s >> 7) & 15, row = s & 127;
        gload16u(z3 + (size_t)lv * ZPLANE + ((size_t)(m0 + row) << 7) + ch * 8,
                 zs + s0 * 8);
    }
    // es window 0 (tt=0, ks=0) into buf 0
    {
        #pragma unroll
        for (int i = 0; i < 2; i++) {
            int s0 = i * 512 + w * 64;
            if (s0 < 768) {
                int s = s0 + l;
                int lv = s >> 8, ch = (s >> 7) & 1, col = s & 127;
                gload16u(e3 + (size_t)lv * EPLANE + ((size_t)col << 7) + ch * 8,
                         es + s0 * 8);
            }
        }
    }
    if (tid < 128) zsl[tid] = zsums[m0 + tid];
    __syncthreads();    // drains vmcnt+lgkm: zs, es window 0, zsl ready

    float best[2][16];
    int   bidx[2][16];
    #pragma unroll
    for (int i2 = 0; i2 < 2; i2++)
        #pragma unroll
        for (int q = 0; q < 16; q++) { best[i2][q] = 3.4e38f; bidx[i2][q] = 0; }

    int cur = 0;
    for (int tt = 0; tt < 16; tt++) {           // 16 t-tiles x 128 cols
        f32x16 am[2], ac[2];
        #pragma unroll
        for (int i2 = 0; i2 < 2; i2++)
            #pragma unroll
            for (int q = 0; q < 16; q++) { am[i2][q] = 0.0f; ac[i2][q] = 0.0f; }

        for (int ks = 0; ks < 8; ks++) {        // K=16 per step
            int g = tt * 8 + ks;
            if (g + 1 < 128) {                  // prefetch next window -> other buf
                int ng = g + 1;
                int ntt = ng >> 3, nks = ng & 7;
                #pragma unroll
                for (int i = 0; i < 2; i++) {
                    int s0 = i * 512 + w * 64;
                    if (s0 < 768) {
                        int s = s0 + l;
                        int lv = s >> 8, ch = (s >> 7) & 1, col = s & 127;
                        gload16u(e3 + (size_t)lv * EPLANE
                                    + ((size_t)(ntt * 128 + col) << 7) + nks * 16 + ch * 8,
                                 es + (cur ^ 1) * 6144 + s0 * 8);
                    }
                }
            }

            short8 a[2][3], b[3];
            #pragma unroll
            for (int i2 = 0; i2 < 2; i2++)
                #pragma unroll
                for (int lv = 0; lv < 3; lv++)
                    a[i2][lv] = *reinterpret_cast<const short8*>(
                        zs + ((lv * 16 + ks * 2 + h) * 128 + wm * 64 + i2 * 32 + r32) * 8);
            #pragma unroll
            for (int lv = 0; lv < 3; lv++)
                b[lv] = *reinterpret_cast<const short8*>(
                    es + cur * 6144 + ((lv * 2 + h) * 128 + wn * 32 + r32) * 8);

            #pragma unroll
            for (int i2 = 0; i2 < 2; i2++) {
                am[i2] = __builtin_amdgcn_mfma_f32_32x32x16_bf16(a[i2][0], b[0], am[i2], 0, 0, 0);
                ac[i2] = __builtin_amdgcn_mfma_f32_32x32x16_bf16(a[i2][0], b[1], ac[i2], 0, 0, 0);
                ac[i2] = __builtin_amdgcn_mfma_f32_32x32x16_bf16(a[i2][1], b[0], ac[i2], 0, 0, 0);
                ac[i2] = __builtin_amdgcn_mfma_f32_32x32x16_bf16(a[i2][0], b[2], ac[i2], 0, 0, 0);
                ac[i2] = __builtin_amdgcn_mfma_f32_32x32x16_bf16(a[i2][1], b[1], ac[i2], 0, 0, 0);
                ac[i2] = __builtin_amdgcn_mfma_f32_32x32x16_bf16(a[i2][2], b[0], ac[i2], 0, 0, 0);
            }
            __syncthreads();   // readers done with cur; prefetch landed in cur^1
            cur ^= 1;
        }

        // epilogue: online argmin update (n ascending across tt; strict <)
        const int nbase = tt * 128 + wn * 32 + r32;
        const float eqv = eq[nbase];
        #pragma unroll
        for (int i2 = 0; i2 < 2; i2++) {
            #pragma unroll
            for (int q = 0; q < 16; q++) {
                const int row = wm * 64 + i2 * 32 + ((q & 3) + 8 * (q >> 2) + 4 * h);
                float zse = zsl[row] + eqv;          // fp32 round at ~128 scale
                float dot = am[i2][q] + ac[i2][q];
                float val = zse - 2.0f * dot;
                if (val < best[i2][q]) { best[i2][q] = val; bidx[i2][q] = nbase; }
            }
        }
    }

    // reduce over the 32 col-lanes (offs <32 stay within each half)
    #pragma unroll
    for (int off = 16; off >= 1; off >>= 1) {
        #pragma unroll
        for (int i2 = 0; i2 < 2; i2++)
            #pragma unroll
            for (int q = 0; q < 16; q++) {
                float ov = __shfl_xor(best[i2][q], off);
                int   oi = __shfl_xor(bidx[i2][q], off);
                if (ov < best[i2][q] || (ov == best[i2][q] && oi < bidx[i2][q])) {
                    best[i2][q] = ov; bidx[i2][q] = oi;
                }
            }
    }
    if (r32 == 0) {            // lanes 0 and 32 per wave
        #pragma unroll
        for (int i2 = 0; i2 < 2; i2++)
            #pragma unroll
            for (int q = 0; q < 16; q++) {
                int row = wm * 64 + i2 * 32 + ((q & 3) + 8 * (q >> 2) + 4 * h);
                cand_v[row * 4 + wn] = best[i2][q];
                cand_i[row * 4 + wn] = bidx[i2][q];
            }
    }
    __syncthreads();
    if (tid < 128) {           // final: 4 wn-candidates, ascending n; tie -> lower idx
        float bv = cand_v[tid * 4 + 0];
        int   bi = cand_i[tid * 4 + 0];
        #pragma unroll
        for (int j = 1; j < 4; j++) {
            float v = cand_v[tid * 4 + j];
            int   ii = cand_i[tid * 4 + j];
            if (v < bv || (v == bv && ii < bi)) { bv = v; bi = ii; }
        }
        out_idx[m0 + tid] = bi;
    }
}

// ---------------- min_encodings one-hot fill (proven) ----------------
__global__ __launch_bounds__(256) void minenc_kernel(const int* __restrict__ idx,
                                                     float* __restrict__ out) {
    size_t i = (size_t)blockIdx.x * blockDim.x + threadIdx.x;
    const size_t total = (size_t)M_ROWS * (NE / 2);
    const size_t stride = (size_t)gridDim.x * blockDim.x;
    for (; i < total; i += stride) {
        int row = (int)(i >> 10);
        int col = (int)(i & 1023) << 1;
        int id = idx[row];
        float2 v;
        v.x = (col == id) ? 1.0f : 0.0f;
        v.y = (col + 1 == id) ? 1.0f : 0.0f;
        reinterpret_cast<float2*>(out)[i] = v;
    }
}

// ---------------- gather z_q, write z_q_st, idx(float), loss partials, histogram ----
__global__ __launch_bounds__(256) void gather_kernel(const float* __restrict__ z,
                                                     const float* __restrict__ emb,
                                                     const int* __restrict__ idx,
                                                     float* __restrict__ out,
                                                     float* __restrict__ partial,
                                                     int* __restrict__ hist) {
    __shared__ float red[256];
    const int tid = threadIdx.x;
    const int rl = tid >> 4;
    const int sub = tid & 15;
    const int row = blockIdx.x * 16 + rl;
    const int id = idx[row];

    const float* zr = z + (size_t)row * EDIM + sub * 8;
    const float* er = emb + (size_t)id * EDIM + sub * 8;
    float* outr = out + O_ZQ + (size_t)row * EDIM + sub * 8;

    float4 z0 = reinterpret_cast<const float4*>(zr)[0];
    float4 z1 = reinterpret_cast<const float4*>(zr)[1];
    float4 e0 = reinterpret_cast<const float4*>(er)[0];
    float4 e1 = reinterpret_cast<const float4*>(er)[1];

    float zz[8] = {z0.x, z0.y, z0.z, z0.w, z1.x, z1.y, z1.z, z1.w};
    float ee[8] = {e0.x, e0.y, e0.z, e0.w, e1.x, e1.y, e1.z, e1.w};
    float s = 0.0f;
    #pragma unroll
    for (int j = 0; j < 8; j++) {
        float d = ee[j] - zz[j];
        outr[j] = zz[j] + d;
        s += d * d;
    }
    if (sub == 0) {
        atomicAdd(&hist[id], 1);
        out[O_IDX + row] = (float)id;
    }
    red[tid] = s;
    __syncthreads();
    #pragma unroll
    for (int o = 128; o >= 1; o >>= 1) {
        if (tid < o) red[tid] += red[tid + o];
        __syncthreads();
    }
    if (tid == 0) partial[blockIdx.x] = red[0];
}

// ---------------- finalize: loss + perplexity (proven) ----------------
__global__ __launch_bounds__(256) void finalize_kernel(const float* __restrict__ partial,
                                                       const int* __restrict__ hist,
                                                       float* __restrict__ out) {
    __shared__ float red[256];
    const int tid = threadIdx.x;
    float s = 0.0f;
    for (int i = 0; i < 8; i++) s += partial[tid * 8 + i];
    red[tid] = s;
    __syncthreads();
    #pragma unroll
    for (int o = 128; o >= 1; o >>= 1) {
        if (tid < o) red[tid] += red[tid + o];
        __syncthreads();
    }
    if (tid == 0) out[O_LOSS] = 1.25f * red[0] / (float)((size_t)M_ROWS * EDIM);
    __syncthreads();

    float h = 0.0f;
    for (int i = 0; i < 8; i++) {
        float p = (float)hist[tid * 8 + i] * (1.0f / (float)M_ROWS);
        h += p * logf(p + 1e-10f);
    }
    red[tid] = h;
    __syncthreads();
    #pragma unroll
    for (int o = 128; o >= 1; o >>= 1) {
        if (tid < o) red[tid] += red[tid + o];
        __syncthreads();
    }
    if (tid == 0) out[O_PERP] = expf(-red[0]);
}

extern "C" void kernel_launch(void* const* d_in, const int* in_sizes, int n_in,
                              void* d_out, int out_size, void* d_ws, size_t ws_size,
                              hipStream_t stream) {
    const float* z   = (const float*)d_in[0];
    const float* emb = (const float*)d_in[1];
    float* out = (float*)d_out;

    char* ws = (char*)d_ws;
    float* eq    = (float*)ws;                    // 2048 f32
    int*   idx   = (int*)(ws + 8192);             // 32768 i32
    int*   hist  = (int*)(ws + 139264);           // 2048 i32
    float* part  = (float*)(ws + 147456);         // 2048 f32
    float* zsums = (float*)(ws + 155648);         // 32768 f32

    // bf16-level scratch inside the minenc output region (overwritten by minenc
    // after argmin consumed it; +2 floats for 16B alignment). 26.7MB of 268MB.
    u16* Z3 = (u16*)(out + O_MINENC + 2);
    u16* E3 = Z3 + 3 * (size_t)ZPLANE;

    prep_kernel<<<4352, 256, 0, stream>>>(z, emb, Z3, E3);
    zsum_kernel<<<256, 256, 0, stream>>>(z, zsums);
    eq_kernel<<<NE, 64, 0, stream>>>(emb, eq, hist);
    argmin_mfma_kernel<<<256, 512, 0, stream>>>(Z3, E3, zsums, eq, idx);
    minenc_kernel<<<8192, 256, 0, stream>>>(idx, out + O_MINENC);
    gather_kernel<<<M_ROWS / 16, 256, 0, stream>>>(z, emb, idx, out, part, hist);
    finalize_kernel<<<1, 256, 0, stream>>>(part, hist, out);
}

// Round 9
// 174.557 us; speedup vs baseline: 2.2641x; 1.2317x over previous
//
#include <hip/hip_runtime.h>
#include <hip/hip_bf16.h>
#include <hip/hip_fp16.h>
#include <math.h>

#define M_ROWS 32768
#define NE 2048
#define EDIM 128

// d_out element offsets (fp32)
#define O_LOSS 0
#define O_ZQ 1
#define O_PERP 4194305
#define O_MINENC 4194306
#define O_IDX 71303170ll

#define AS1 __attribute__((address_space(1)))
#define AS3 __attribute__((address_space(3)))

typedef unsigned short u16;
typedef __attribute__((ext_vector_type(8))) _Float16 half8;  // 8 f16 (4 VGPRs)
typedef __attribute__((ext_vector_type(16))) float f32x16;   // 32x32 MFMA acc

#define ZPLANE2 4194304   // 32768*128 (u16 elems per z plane)
#define EPLANE2 262144    // 2048*128  (u16 elems per e plane)

// async global->LDS DMA, 16B/lane; LDS dest = wave-uniform base + lane*16.
__device__ __forceinline__ void gload16u(const u16* g, u16* l) {
    __builtin_amdgcn_global_load_lds((const AS1 void*)g, (AS3 void*)l, 16, 0, 0);
}

// ---------------- prep: 2-level fp16 split; e pre-scaled by 2048 (exact pow2) ----
// z  = zh + zm + r,  |r| <= 2^-24|z|  (fp16 RNE twice; residual subtract exact)
// e' = 2048*e = eh + em + r',         |r'| <= 2^-24|e'|
// dot recovered as (zh.eh + zh.em + zm.eh) * 2^-10 * ... (2/2048 applied in argmin).
// Dropped terms (zm.em, r-terms) ~1e-10 in d-space << ulp(128)/2 = 7.6e-6.
__global__ __launch_bounds__(256) void prep_kernel(const float* __restrict__ z,
                                                   const float* __restrict__ emb,
                                                   u16* __restrict__ z2,
                                                   u16* __restrict__ e2) {
    const int ZQ = 1048576, EQ = 65536;            // float4 group counts
    int i = blockIdx.x * 256 + threadIdx.x;
    if (i >= ZQ + EQ) return;
    const bool isz = (i < ZQ);
    const float4 v = isz ? reinterpret_cast<const float4*>(z)[i]
                         : reinterpret_cast<const float4*>(emb)[i - ZQ];
    const float sc = isz ? 1.0f : 2048.0f;         // exact scaling
    float fv[4] = {v.x * sc, v.y * sc, v.z * sc, v.w * sc};
    u16 hs[4], ms[4];
    #pragma unroll
    for (int j = 0; j < 4; j++) {
        __half hh = __float2half_rn(fv[j]);
        float fh = __half2float(hh);
        float r = fv[j] - fh;                      // exact (Sterbenz / zero cases)
        __half hm = __float2half_rn(r);
        hs[j] = __half_as_ushort(hh);
        ms[j] = __half_as_ushort(hm);
    }
    u16* base = isz ? z2 : e2;
    size_t PL = isz ? (size_t)ZPLANE2 : (size_t)EPLANE2;
    size_t off = (size_t)(isz ? i : (i - ZQ)) * 4;
    reinterpret_cast<ushort4*>(base + off)[0]      = make_ushort4(hs[0], hs[1], hs[2], hs[3]);
    reinterpret_cast<ushort4*>(base + PL + off)[0] = make_ushort4(ms[0], ms[1], ms[2], ms[3]);
}

// ---------------- zsums: per-row ||z||^2, bitwise identical to rounds 5-8 ----------
__global__ __launch_bounds__(256) void zsum_kernel(const float* __restrict__ z,
                                                   float* __restrict__ zsums) {
    __shared__ float zsh[128 * 128];
    const int tid = threadIdx.x;
    const int m0 = blockIdx.x * 128;
    for (int i = tid; i < 4096; i += 256) {
        int r = i >> 5, cc = i & 31;
        float4 v = reinterpret_cast<const float4*>(z + (size_t)(m0 + r) * EDIM)[cc];
        *reinterpret_cast<float4*>(&zsh[r * 128 + ((cc ^ ((r >> 3) & 7)) << 2)]) = v;
    }
    __syncthreads();
    if (tid < 128) {
        const float* zr = &zsh[tid * 128];
        const int key = (tid >> 3) & 7;
        float s = 0.0f;
        for (int cc = 0; cc < 32; cc++) {          // k-ascending (proven order)
            float4 v = *reinterpret_cast<const float4*>(zr + ((cc ^ key) << 2));
            s += v.x * v.x;
            s += v.y * v.y;
            s += v.z * v.z;
            s += v.w * v.w;
        }
        zsums[m0 + tid] = s;
    }
}

// ---------------- eq = ||e_n||^2, and zero the histogram (proven) ----------------
__global__ void eq_kernel(const float* __restrict__ emb, float* __restrict__ eq,
                          int* __restrict__ hist) {
    int n = blockIdx.x;
    int lane = threadIdx.x;
    float v0 = emb[(size_t)n * EDIM + lane];
    float v1 = emb[(size_t)n * EDIM + 64 + lane];
    float s = v0 * v0 + v1 * v1;
    #pragma unroll
    for (int off = 32; off >= 1; off >>= 1) s += __shfl_down(s, off);
    if (lane == 0) { eq[n] = s; hist[n] = 0; }
}

// ---------------- MFMA argmin: 3-term fp16 split, 32x32x16, 2 blocks/CU ----------
// val = fl(fl(zsum+eq) - fl(am+ac)*2^-10)  (2^-10 = 2/2048 exact).
// am = dot(zh,eh') dominant fp32 chain; ac = zh.em' + zm.eh' corrections.
// 512 blocks x 64 rows; 256 thr = 4 waves (wn = wave = col quarter).
// Per wave: AM=2 (rows i2*32+r32), AN=1 (cols wn*32+r32); tt tile = 128 cols.
// es windows K=32, ping-pong (64 barriers/block). LDS ~66KB -> 2 blocks/CU:
// co-resident block fills this block's barrier/DMA drain (m114 overlap).
// zs: [lv][16 ch][64 row][8 halves]; es: [buf][lv][4 ch][128 col][8 halves].
// All LDS reads: 32 consecutive rows x 16B = contiguous 512B -> conflict-free.
__global__ __launch_bounds__(256, 2) void argmin_mfma_kernel(
    const u16* __restrict__ z2, const u16* __restrict__ e2,
    const float* __restrict__ zsums, const float* __restrict__ eq,
    int* __restrict__ out_idx)
{
    __shared__ __align__(16) u16 zs[16384];     // 32 KB
    __shared__ __align__(16) u16 es[16384];     // 2 x 16 KB ping-pong
    __shared__ float zsl[64];
    __shared__ float cand_v[256];
    __shared__ int   cand_i[256];

    const int tid = threadIdx.x;
    const int w = tid >> 6, l = tid & 63;
    const int wn = w;                   // col quarter
    const int h = l >> 5, r32 = l & 31;
    const int m0 = blockIdx.x * 64;

    // prologue: DMA zs (2 levels, full K) -- 8 gloads/thread
    #pragma unroll
    for (int j = 0; j < 8; j++) {
        int s0 = j * 256 + w * 64;               // wave-uniform slot base
        int s = s0 + l;
        int lv = s >> 10, ch = (s >> 6) & 15, row = s & 63;
        gload16u(z2 + (size_t)lv * ZPLANE2 + ((size_t)(m0 + row) << 7) + ch * 8,
                 zs + s0 * 8);
    }
    // es window 0 (tt=0, kh=0)
    #pragma unroll
    for (int i = 0; i < 4; i++) {
        int s0 = i * 256 + w * 64;
        int s = s0 + l;
        int lv = s >> 9, ch = (s >> 7) & 3, col = s & 127;
        gload16u(e2 + (size_t)lv * EPLANE2 + ((size_t)col << 7) + ch * 8,
                 es + s0 * 8);
    }
    if (tid < 64) zsl[tid] = zsums[m0 + tid];
    __syncthreads();    // drains vmcnt: zs + es window 0 + zsl ready

    float best[2][16];
    int   bidx[2][16];
    #pragma unroll
    for (int i2 = 0; i2 < 2; i2++)
        #pragma unroll
        for (int q = 0; q < 16; q++) { best[i2][q] = 3.4e38f; bidx[i2][q] = 0; }

    int cur = 0;
    for (int tt = 0; tt < 16; tt++) {           // 16 t-tiles x 128 cols
        f32x16 am[2], ac[2];
        #pragma unroll
        for (int i2 = 0; i2 < 2; i2++)
            #pragma unroll
            for (int q = 0; q < 16; q++) { am[i2][q] = 0.0f; ac[i2][q] = 0.0f; }

        for (int kh = 0; kh < 4; kh++) {        // K=32 per window
            int g = tt * 4 + kh;
            if (g + 1 < 64) {                   // prefetch next window -> other buf
                int ng = g + 1;
                int ntt = ng >> 2, nkh = ng & 3;
                #pragma unroll
                for (int i = 0; i < 4; i++) {
                    int s0 = i * 256 + w * 64;
                    int s = s0 + l;
                    int lv = s >> 9, ch = (s >> 7) & 3, col = s & 127;
                    gload16u(e2 + (size_t)lv * EPLANE2
                                + ((size_t)(ntt * 128 + col) << 7) + nkh * 32 + ch * 8,
                             es + (cur ^ 1) * 8192 + s0 * 8);
                }
            }

            const u16* esb = es + cur * 8192;
            #pragma unroll
            for (int st = 0; st < 2; st++) {    // two K=16 MFMA steps per window
                half8 a[2][2], b[2];
                #pragma unroll
                for (int i2 = 0; i2 < 2; i2++)
                    #pragma unroll
                    for (int lv = 0; lv < 2; lv++)
                        a[i2][lv] = *reinterpret_cast<const half8*>(
                            zs + ((lv * 16 + kh * 4 + st * 2 + h) * 64 + i2 * 32 + r32) * 8);
                #pragma unroll
                for (int lv = 0; lv < 2; lv++)
                    b[lv] = *reinterpret_cast<const half8*>(
                        esb + ((lv * 4 + st * 2 + h) * 128 + wn * 32 + r32) * 8);

                #pragma unroll
                for (int i2 = 0; i2 < 2; i2++) {
                    am[i2] = __builtin_amdgcn_mfma_f32_32x32x16_f16(a[i2][0], b[0], am[i2], 0, 0, 0);
                    ac[i2] = __builtin_amdgcn_mfma_f32_32x32x16_f16(a[i2][0], b[1], ac[i2], 0, 0, 0);
                    ac[i2] = __builtin_amdgcn_mfma_f32_32x32x16_f16(a[i2][1], b[0], ac[i2], 0, 0, 0);
                }
            }
            __syncthreads();   // readers done with cur; prefetch landed in cur^1
            cur ^= 1;
        }

        // epilogue: online argmin update (n ascending across tt; strict <)
        const int n = tt * 128 + wn * 32 + r32;
        const float eqv = eq[n];
        #pragma unroll
        for (int i2 = 0; i2 < 2; i2++) {
            #pragma unroll
            for (int q = 0; q < 16; q++) {
                const int row = i2 * 32 + ((q & 3) + 8 * (q >> 2) + 4 * h);
                float zse = zsl[row] + eqv;              // fp32 round at ~128 scale
                float dotp = am[i2][q] + ac[i2][q];      // one round
                float val = zse - dotp * 0.0009765625f;  // *2^-10 exact; one round
                if (val < best[i2][q]) { best[i2][q] = val; bidx[i2][q] = n; }
            }
        }
    }

    // reduce over the 32 col-lanes (offs <32 stay within each half)
    #pragma unroll
    for (int off = 16; off >= 1; off >>= 1) {
        #pragma unroll
        for (int i2 = 0; i2 < 2; i2++)
            #pragma unroll
            for (int q = 0; q < 16; q++) {
                float ov = __shfl_xor(best[i2][q], off);
                int   oi = __shfl_xor(bidx[i2][q], off);
                if (ov < best[i2][q] || (ov == best[i2][q] && oi < bidx[i2][q])) {
                    best[i2][q] = ov; bidx[i2][q] = oi;
                }
            }
    }
    if (r32 == 0) {            // lanes 0 and 32 per wave
        #pragma unroll
        for (int i2 = 0; i2 < 2; i2++)
            #pragma unroll
            for (int q = 0; q < 16; q++) {
                int row = i2 * 32 + ((q & 3) + 8 * (q >> 2) + 4 * h);
                cand_v[row * 4 + wn] = best[i2][q];
                cand_i[row * 4 + wn] = bidx[i2][q];
            }
    }
    __syncthreads();
    if (tid < 64) {            // final: 4 wn-candidates; tie -> lower idx
        float bv = cand_v[tid * 4 + 0];
        int   bi = cand_i[tid * 4 + 0];
        #pragma unroll
        for (int j = 1; j < 4; j++) {
            float v = cand_v[tid * 4 + j];
            int   ii = cand_i[tid * 4 + j];
            if (v < bv || (v == bv && ii < bi)) { bv = v; bi = ii; }
        }
        out_idx[m0 + tid] = bi;
    }
}

// ---------------- min_encodings one-hot fill (proven) ----------------
__global__ __launch_bounds__(256) void minenc_kernel(const int* __restrict__ idx,
                                                     float* __restrict__ out) {
    size_t i = (size_t)blockIdx.x * blockDim.x + threadIdx.x;
    const size_t total = (size_t)M_ROWS * (NE / 2);
    const size_t stride = (size_t)gridDim.x * blockDim.x;
    for (; i < total; i += stride) {
        int row = (int)(i >> 10);
        int col = (int)(i & 1023) << 1;
        int id = idx[row];
        float2 v;
        v.x = (col == id) ? 1.0f : 0.0f;
        v.y = (col + 1 == id) ? 1.0f : 0.0f;
        reinterpret_cast<float2*>(out)[i] = v;
    }
}

// ---------------- gather z_q, write z_q_st, idx(float), loss partials, histogram ----
__global__ __launch_bounds__(256) void gather_kernel(const float* __restrict__ z,
                                                     const float* __restrict__ emb,
                                                     const int* __restrict__ idx,
                                                     float* __restrict__ out,
                                                     float* __restrict__ partial,
                                                     int* __restrict__ hist) {
    __shared__ float red[256];
    const int tid = threadIdx.x;
    const int rl = tid >> 4;
    const int sub = tid & 15;
    const int row = blockIdx.x * 16 + rl;
    const int id = idx[row];

    const float* zr = z + (size_t)row * EDIM + sub * 8;
    const float* er = emb + (size_t)id * EDIM + sub * 8;
    float* outr = out + O_ZQ + (size_t)row * EDIM + sub * 8;

    float4 z0 = reinterpret_cast<const float4*>(zr)[0];
    float4 z1 = reinterpret_cast<const float4*>(zr)[1];
    float4 e0 = reinterpret_cast<const float4*>(er)[0];
    float4 e1 = reinterpret_cast<const float4*>(er)[1];

    float zz[8] = {z0.x, z0.y, z0.z, z0.w, z1.x, z1.y, z1.z, z1.w};
    float ee[8] = {e0.x, e0.y, e0.z, e0.w, e1.x, e1.y, e1.z, e1.w};
    float s = 0.0f;
    #pragma unroll
    for (int j = 0; j < 8; j++) {
        float d = ee[j] - zz[j];
        outr[j] = zz[j] + d;
        s += d * d;
    }
    if (sub == 0) {
        atomicAdd(&hist[id], 1);
        out[O_IDX + row] = (float)id;
    }
    red[tid] = s;
    __syncthreads();
    #pragma unroll
    for (int o = 128; o >= 1; o >>= 1) {
        if (tid < o) red[tid] += red[tid + o];
        __syncthreads();
    }
    if (tid == 0) partial[blockIdx.x] = red[0];
}

// ---------------- finalize: loss + perplexity (proven) ----------------
__global__ __launch_bounds__(256) void finalize_kernel(const float* __restrict__ partial,
                                                       const int* __restrict__ hist,
                                                       float* __restrict__ out) {
    __shared__ float red[256];
    const int tid = threadIdx.x;
    float s = 0.0f;
    for (int i = 0; i < 8; i++) s += partial[tid * 8 + i];
    red[tid] = s;
    __syncthreads();
    #pragma unroll
    for (int o = 128; o >= 1; o >>= 1) {
        if (tid < o) red[tid] += red[tid + o];
        __syncthreads();
    }
    if (tid == 0) out[O_LOSS] = 1.25f * red[0] / (float)((size_t)M_ROWS * EDIM);
    __syncthreads();

    float h = 0.0f;
    for (int i = 0; i < 8; i++) {
        float p = (float)hist[tid * 8 + i] * (1.0f / (float)M_ROWS);
        h += p * logf(p + 1e-10f);
    }
    red[tid] = h;
    __syncthreads();
    #pragma unroll
    for (int o = 128; o >= 1; o >>= 1) {
        if (tid < o) red[tid] += red[tid + o];
        __syncthreads();
    }
    if (tid == 0) out[O_PERP] = expf(-red[0]);
}

extern "C" void kernel_launch(void* const* d_in, const int* in_sizes, int n_in,
                              void* d_out, int out_size, void* d_ws, size_t ws_size,
                              hipStream_t stream) {
    const float* z   = (const float*)d_in[0];
    const float* emb = (const float*)d_in[1];
    float* out = (float*)d_out;

    char* ws = (char*)d_ws;
    float* eq    = (float*)ws;                    // 2048 f32
    int*   idx   = (int*)(ws + 8192);             // 32768 i32
    int*   hist  = (int*)(ws + 139264);           // 2048 i32
    float* part  = (float*)(ws + 147456);         // 2048 f32
    float* zsums = (float*)(ws + 155648);         // 32768 f32

    // fp16-level scratch inside the minenc output region (overwritten by minenc
    // after argmin consumed it; +2 floats keeps 16B alignment). ~18MB of 268MB.
    u16* Z2 = (u16*)(out + O_MINENC + 2);
    u16* E2 = Z2 + 2 * (size_t)ZPLANE2;

    prep_kernel<<<4352, 256, 0, stream>>>(z, emb, Z2, E2);
    zsum_kernel<<<256, 256, 0, stream>>>(z, zsums);
    eq_kernel<<<NE, 64, 0, stream>>>(emb, eq, hist);
    argmin_mfma_kernel<<<512, 256, 0, stream>>>(Z2, E2, zsums, eq, idx);
    minenc_kernel<<<8192, 256, 0, stream>>>(idx, out + O_MINENC);
    gather_kernel<<<M_ROWS / 16, 256, 0, stream>>>(z, emb, idx, out, part, hist);
    finalize_kernel<<<1, 256, 0, stream>>>(part, hist, out);
}

// Round 10
// 143.647 us; speedup vs baseline: 2.7513x; 1.2152x over previous
//
#include <hip/hip_runtime.h>
#include <hip/hip_bf16.h>
#include <hip/hip_fp16.h>
#include <math.h>

#define M_ROWS 32768
#define NE 2048
#define EDIM 128

// d_out element offsets (fp32)
#define O_LOSS 0
#define O_ZQ 1
#define O_PERP 4194305
#define O_MINENC 4194306
#define O_IDX 71303170ll

#define AS1 __attribute__((address_space(1)))
#define AS3 __attribute__((address_space(3)))

typedef unsigned short u16;
typedef __attribute__((ext_vector_type(8))) _Float16 half8;  // 8 f16 (4 VGPRs)
typedef __attribute__((ext_vector_type(16))) float f32x16;   // 32x32 MFMA acc

#define ZPLANE2 4194304   // 32768*128 (u16 elems per z plane)
#define EPLANE2 262144    // 2048*128  (u16 elems per e plane)

// async global->LDS DMA, 16B/lane; LDS dest = wave-uniform base + lane*16.
__device__ __forceinline__ void gload16u(const u16* g, u16* l) {
    __builtin_amdgcn_global_load_lds((const AS1 void*)g, (AS3 void*)l, 16, 0, 0);
}

// ---------------- prep: 2-level fp16 split; e pre-scaled by 2048 (exact pow2) ----
__global__ __launch_bounds__(256) void prep_kernel(const float* __restrict__ z,
                                                   const float* __restrict__ emb,
                                                   u16* __restrict__ z2,
                                                   u16* __restrict__ e2) {
    const int ZQ = 1048576, EQ = 65536;            // float4 group counts
    int i = blockIdx.x * 256 + threadIdx.x;
    if (i >= ZQ + EQ) return;
    const bool isz = (i < ZQ);
    const float4 v = isz ? reinterpret_cast<const float4*>(z)[i]
                         : reinterpret_cast<const float4*>(emb)[i - ZQ];
    const float sc = isz ? 1.0f : 2048.0f;         // exact scaling
    float fv[4] = {v.x * sc, v.y * sc, v.z * sc, v.w * sc};
    u16 hs[4], ms[4];
    #pragma unroll
    for (int j = 0; j < 4; j++) {
        __half hh = __float2half_rn(fv[j]);
        float fh = __half2float(hh);
        float r = fv[j] - fh;                      // exact (Sterbenz / zero cases)
        __half hm = __float2half_rn(r);
        hs[j] = __half_as_ushort(hh);
        ms[j] = __half_as_ushort(hm);
    }
    u16* base = isz ? z2 : e2;
    size_t PL = isz ? (size_t)ZPLANE2 : (size_t)EPLANE2;
    size_t off = (size_t)(isz ? i : (i - ZQ)) * 4;
    reinterpret_cast<ushort4*>(base + off)[0]      = make_ushort4(hs[0], hs[1], hs[2], hs[3]);
    reinterpret_cast<ushort4*>(base + PL + off)[0] = make_ushort4(ms[0], ms[1], ms[2], ms[3]);
}

// ---------------- zsums: per-row ||z||^2, bitwise identical to rounds 5-9 ----------
__global__ __launch_bounds__(256) void zsum_kernel(const float* __restrict__ z,
                                                   float* __restrict__ zsums) {
    __shared__ float zsh[128 * 128];
    const int tid = threadIdx.x;
    const int m0 = blockIdx.x * 128;
    for (int i = tid; i < 4096; i += 256) {
        int r = i >> 5, cc = i & 31;
        float4 v = reinterpret_cast<const float4*>(z + (size_t)(m0 + r) * EDIM)[cc];
        *reinterpret_cast<float4*>(&zsh[r * 128 + ((cc ^ ((r >> 3) & 7)) << 2)]) = v;
    }
    __syncthreads();
    if (tid < 128) {
        const float* zr = &zsh[tid * 128];
        const int key = (tid >> 3) & 7;
        float s = 0.0f;
        for (int cc = 0; cc < 32; cc++) {          // k-ascending (proven order)
            float4 v = *reinterpret_cast<const float4*>(zr + ((cc ^ key) << 2));
            s += v.x * v.x;
            s += v.y * v.y;
            s += v.z * v.z;
            s += v.w * v.w;
        }
        zsums[m0 + tid] = s;
    }
}

// ---------------- eq = ||e_n||^2, and zero the histogram (proven) ----------------
__global__ void eq_kernel(const float* __restrict__ emb, float* __restrict__ eq,
                          int* __restrict__ hist) {
    int n = blockIdx.x;
    int lane = threadIdx.x;
    float v0 = emb[(size_t)n * EDIM + lane];
    float v1 = emb[(size_t)n * EDIM + 64 + lane];
    float s = v0 * v0 + v1 * v1;
    #pragma unroll
    for (int off = 32; off >= 1; off >>= 1) s += __shfl_down(s, off);
    if (lane == 0) { eq[n] = s; hist[n] = 0; }
}

// ---------------- MFMA argmin (round-9 proven core) + fused output writes ----------
// WE=1: this block also zero-fills its own 64-row min_encodings stripe (stores
// spread across the 16 t-tiles to hide under MFMA/DMA stalls), then writes the
// one-hot 1.0s, fp32 idx, and histogram in the epilogue. Ordering: every
// __syncthreads drains vmcnt (compiler emits s_waitcnt vmcnt(0) before barrier),
// so the zeros are complete before the 1.0 stores; same block -> same L2.
template<int WE>
__global__ __launch_bounds__(256, 2) void argmin_mfma_kernel(
    const u16* __restrict__ z2, const u16* __restrict__ e2,
    const float* __restrict__ zsums, const float* __restrict__ eq,
    int* __restrict__ out_idx, float* __restrict__ out, int* __restrict__ hist)
{
    __shared__ __align__(16) u16 zs[16384];     // 32 KB
    __shared__ __align__(16) u16 es[16384];     // 2 x 16 KB ping-pong
    __shared__ float zsl[64];
    __shared__ float cand_v[256];
    __shared__ int   cand_i[256];

    const int tid = threadIdx.x;
    const int w = tid >> 6, l = tid & 63;
    const int wn = w;                   // col quarter
    const int h = l >> 5, r32 = l & 31;
    const int m0 = blockIdx.x * 64;

    // prologue: DMA zs (2 levels, full K) -- 8 gloads/thread
    #pragma unroll
    for (int j = 0; j < 8; j++) {
        int s0 = j * 256 + w * 64;               // wave-uniform slot base
        int s = s0 + l;
        int lv = s >> 10, ch = (s >> 6) & 15, row = s & 63;
        gload16u(z2 + (size_t)lv * ZPLANE2 + ((size_t)(m0 + row) << 7) + ch * 8,
                 zs + s0 * 8);
    }
    // es window 0 (tt=0, kh=0)
    #pragma unroll
    for (int i = 0; i < 4; i++) {
        int s0 = i * 256 + w * 64;
        int s = s0 + l;
        int lv = s >> 9, ch = (s >> 7) & 3, col = s & 127;
        gload16u(e2 + (size_t)lv * EPLANE2 + ((size_t)col << 7) + ch * 8,
                 es + s0 * 8);
    }
    if (tid < 64) zsl[tid] = zsums[m0 + tid];
    __syncthreads();    // drains vmcnt: zs + es window 0 + zsl ready

    float best[2][16];
    int   bidx[2][16];
    #pragma unroll
    for (int i2 = 0; i2 < 2; i2++)
        #pragma unroll
        for (int q = 0; q < 16; q++) { best[i2][q] = 3.4e38f; bidx[i2][q] = 0; }

    float2* me2 = reinterpret_cast<float2*>(out + O_MINENC + (size_t)m0 * NE);

    int cur = 0;
    for (int tt = 0; tt < 16; tt++) {           // 16 t-tiles x 128 cols
        if constexpr (WE) {                     // zero-fill 4 rows of the stripe
            const float2 zz2 = make_float2(0.0f, 0.0f);
            #pragma unroll
            for (int j = 0; j < 16; j++)
                me2[tt * 4096 + j * 256 + tid] = zz2;
        }

        f32x16 am[2], ac[2];
        #pragma unroll
        for (int i2 = 0; i2 < 2; i2++)
            #pragma unroll
            for (int q = 0; q < 16; q++) { am[i2][q] = 0.0f; ac[i2][q] = 0.0f; }

        for (int kh = 0; kh < 4; kh++) {        // K=32 per window
            int g = tt * 4 + kh;
            if (g + 1 < 64) {                   // prefetch next window -> other buf
                int ng = g + 1;
                int ntt = ng >> 2, nkh = ng & 3;
                #pragma unroll
                for (int i = 0; i < 4; i++) {
                    int s0 = i * 256 + w * 64;
                    int s = s0 + l;
                    int lv = s >> 9, ch = (s >> 7) & 3, col = s & 127;
                    gload16u(e2 + (size_t)lv * EPLANE2
                                + ((size_t)(ntt * 128 + col) << 7) + nkh * 32 + ch * 8,
                             es + (cur ^ 1) * 8192 + s0 * 8);
                }
            }

            const u16* esb = es + cur * 8192;
            #pragma unroll
            for (int st = 0; st < 2; st++) {    // two K=16 MFMA steps per window
                half8 a[2][2], b[2];
                #pragma unroll
                for (int i2 = 0; i2 < 2; i2++)
                    #pragma unroll
                    for (int lv = 0; lv < 2; lv++)
                        a[i2][lv] = *reinterpret_cast<const half8*>(
                            zs + ((lv * 16 + kh * 4 + st * 2 + h) * 64 + i2 * 32 + r32) * 8);
                #pragma unroll
                for (int lv = 0; lv < 2; lv++)
                    b[lv] = *reinterpret_cast<const half8*>(
                        esb + ((lv * 4 + st * 2 + h) * 128 + wn * 32 + r32) * 8);

                #pragma unroll
                for (int i2 = 0; i2 < 2; i2++) {
                    am[i2] = __builtin_amdgcn_mfma_f32_32x32x16_f16(a[i2][0], b[0], am[i2], 0, 0, 0);
                    ac[i2] = __builtin_amdgcn_mfma_f32_32x32x16_f16(a[i2][0], b[1], ac[i2], 0, 0, 0);
                    ac[i2] = __builtin_amdgcn_mfma_f32_32x32x16_f16(a[i2][1], b[0], ac[i2], 0, 0, 0);
                }
            }
            __syncthreads();   // readers done with cur; prefetch landed in cur^1
            cur ^= 1;
        }

        // epilogue: online argmin update (n ascending across tt; strict <)
        const int n = tt * 128 + wn * 32 + r32;
        const float eqv = eq[n];
        #pragma unroll
        for (int i2 = 0; i2 < 2; i2++) {
            #pragma unroll
            for (int q = 0; q < 16; q++) {
                const int row = i2 * 32 + ((q & 3) + 8 * (q >> 2) + 4 * h);
                float zse = zsl[row] + eqv;              // fp32 round at ~128 scale
                float dotp = am[i2][q] + ac[i2][q];      // one round
                float val = zse - dotp * 0.0009765625f;  // *2^-10 exact; one round
                if (val < best[i2][q]) { best[i2][q] = val; bidx[i2][q] = n; }
            }
        }
    }

    // reduce over the 32 col-lanes (offs <32 stay within each half)
    #pragma unroll
    for (int off = 16; off >= 1; off >>= 1) {
        #pragma unroll
        for (int i2 = 0; i2 < 2; i2++)
            #pragma unroll
            for (int q = 0; q < 16; q++) {
                float ov = __shfl_xor(best[i2][q], off);
                int   oi = __shfl_xor(bidx[i2][q], off);
                if (ov < best[i2][q] || (ov == best[i2][q] && oi < bidx[i2][q])) {
                    best[i2][q] = ov; bidx[i2][q] = oi;
                }
            }
    }
    if (r32 == 0) {            // lanes 0 and 32 per wave
        #pragma unroll
        for (int i2 = 0; i2 < 2; i2++)
            #pragma unroll
            for (int q = 0; q < 16; q++) {
                int row = i2 * 32 + ((q & 3) + 8 * (q >> 2) + 4 * h);
                cand_v[row * 4 + wn] = best[i2][q];
                cand_i[row * 4 + wn] = bidx[i2][q];
            }
    }
    __syncthreads();           // cand final; all zero-stores drained (vmcnt 0)
    if (tid < 64) {            // final: 4 wn-candidates; tie -> lower idx
        float bv = cand_v[tid * 4 + 0];
        int   bi = cand_i[tid * 4 + 0];
        #pragma unroll
        for (int j = 1; j < 4; j++) {
            float v = cand_v[tid * 4 + j];
            int   ii = cand_i[tid * 4 + j];
            if (v < bv || (v == bv && ii < bi)) { bv = v; bi = ii; }
        }
        out_idx[m0 + tid] = bi;
        out[O_IDX + m0 + tid] = (float)bi;
        atomicAdd(&hist[bi], 1);
        if constexpr (WE)
            out[O_MINENC + (size_t)(m0 + tid) * NE + bi] = 1.0f;
    }
}

// ---------------- min_encodings one-hot fill (fallback path only) ----------------
__global__ __launch_bounds__(256) void minenc_kernel(const int* __restrict__ idx,
                                                     float* __restrict__ out) {
    size_t i = (size_t)blockIdx.x * blockDim.x + threadIdx.x;
    const size_t total = (size_t)M_ROWS * (NE / 2);
    const size_t stride = (size_t)gridDim.x * blockDim.x;
    for (; i < total; i += stride) {
        int row = (int)(i >> 10);
        int col = (int)(i & 1023) << 1;
        int id = idx[row];
        float2 v;
        v.x = (col == id) ? 1.0f : 0.0f;
        v.y = (col + 1 == id) ? 1.0f : 0.0f;
        reinterpret_cast<float2*>(out)[i] = v;
    }
}

// ---------------- gather z_q, write z_q_st, loss partials (idx/hist moved) --------
__global__ __launch_bounds__(256) void gather_kernel(const float* __restrict__ z,
                                                     const float* __restrict__ emb,
                                                     const int* __restrict__ idx,
                                                     float* __restrict__ out,
                                                     float* __restrict__ partial) {
    __shared__ float red[256];
    const int tid = threadIdx.x;
    const int rl = tid >> 4;
    const int sub = tid & 15;
    const int row = blockIdx.x * 16 + rl;
    const int id = idx[row];

    const float* zr = z + (size_t)row * EDIM + sub * 8;
    const float* er = emb + (size_t)id * EDIM + sub * 8;
    float* outr = out + O_ZQ + (size_t)row * EDIM + sub * 8;

    float4 z0 = reinterpret_cast<const float4*>(zr)[0];
    float4 z1 = reinterpret_cast<const float4*>(zr)[1];
    float4 e0 = reinterpret_cast<const float4*>(er)[0];
    float4 e1 = reinterpret_cast<const float4*>(er)[1];

    float zz[8] = {z0.x, z0.y, z0.z, z0.w, z1.x, z1.y, z1.z, z1.w};
    float ee[8] = {e0.x, e0.y, e0.z, e0.w, e1.x, e1.y, e1.z, e1.w};
    float s = 0.0f;
    #pragma unroll
    for (int j = 0; j < 8; j++) {
        float d = ee[j] - zz[j];
        outr[j] = zz[j] + d;      // match reference's z + (z_q - z) rounding
        s += d * d;
    }
    red[tid] = s;
    __syncthreads();
    #pragma unroll
    for (int o = 128; o >= 1; o >>= 1) {
        if (tid < o) red[tid] += red[tid + o];
        __syncthreads();
    }
    if (tid == 0) partial[blockIdx.x] = red[0];
}

// ---------------- finalize: loss + perplexity (proven) ----------------
__global__ __launch_bounds__(256) void finalize_kernel(const float* __restrict__ partial,
                                                       const int* __restrict__ hist,
                                                       float* __restrict__ out) {
    __shared__ float red[256];
    const int tid = threadIdx.x;
    float s = 0.0f;
    for (int i = 0; i < 8; i++) s += partial[tid * 8 + i];
    red[tid] = s;
    __syncthreads();
    #pragma unroll
    for (int o = 128; o >= 1; o >>= 1) {
        if (tid < o) red[tid] += red[tid + o];
        __syncthreads();
    }
    if (tid == 0) out[O_LOSS] = 1.25f * red[0] / (float)((size_t)M_ROWS * EDIM);
    __syncthreads();

    float h = 0.0f;
    for (int i = 0; i < 8; i++) {
        float p = (float)hist[tid * 8 + i] * (1.0f / (float)M_ROWS);
        h += p * logf(p + 1e-10f);
    }
    red[tid] = h;
    __syncthreads();
    #pragma unroll
    for (int o = 128; o >= 1; o >>= 1) {
        if (tid < o) red[tid] += red[tid + o];
        __syncthreads();
    }
    if (tid == 0) out[O_PERP] = expf(-red[0]);
}

extern "C" void kernel_launch(void* const* d_in, const int* in_sizes, int n_in,
                              void* d_out, int out_size, void* d_ws, size_t ws_size,
                              hipStream_t stream) {
    const float* z   = (const float*)d_in[0];
    const float* emb = (const float*)d_in[1];
    float* out = (float*)d_out;

    char* ws = (char*)d_ws;
    float* eq    = (float*)ws;                    // 2048 f32
    int*   idx   = (int*)(ws + 8192);             // 32768 i32
    int*   hist  = (int*)(ws + 139264);           // 2048 i32
    float* part  = (float*)(ws + 147456);         // 2048 f32
    float* zsums = (float*)(ws + 155648);         // 32768 f32

    const bool big_ws = (ws_size >= (size_t)(40u << 20));   // fixed per session
    u16 *Z2, *E2;
    if (big_ws) {                                 // planes in scratch
        Z2 = (u16*)(ws + (4u << 20));             // 16.8 MB
        E2 = (u16*)(ws + (24u << 20));            // 1 MB
    } else {                                      // round-9 fallback: planes in
        Z2 = (u16*)(out + O_MINENC + 2);          // minenc region, minenc kernel
        E2 = Z2 + 2 * (size_t)ZPLANE2;            // rewrites it afterwards
    }

    prep_kernel<<<4352, 256, 0, stream>>>(z, emb, Z2, E2);
    zsum_kernel<<<256, 256, 0, stream>>>(z, zsums);
    eq_kernel<<<NE, 64, 0, stream>>>(emb, eq, hist);
    if (big_ws) {
        argmin_mfma_kernel<1><<<512, 256, 0, stream>>>(Z2, E2, zsums, eq, idx, out, hist);
    } else {
        argmin_mfma_kernel<0><<<512, 256, 0, stream>>>(Z2, E2, zsums, eq, idx, out, hist);
        minenc_kernel<<<8192, 256, 0, stream>>>(idx, out + O_MINENC);
    }
    gather_kernel<<<M_ROWS / 16, 256, 0, stream>>>(z, emb, idx, out, part);
    finalize_kernel<<<1, 256, 0, stream>>>(part, hist, out);
}

// Round 11
// 132.269 us; speedup vs baseline: 2.9880x; 1.0860x over previous
//
#include <hip/hip_runtime.h>
#include <hip/hip_bf16.h>
#include <hip/hip_fp16.h>
#include <math.h>

#define M_ROWS 32768
#define NE 2048
#define EDIM 128

// d_out element offsets (fp32)
#define O_LOSS 0
#define O_ZQ 1
#define O_PERP 4194305
#define O_MINENC 4194306
#define O_IDX 71303170ll

#define AS1 __attribute__((address_space(1)))
#define AS3 __attribute__((address_space(3)))

typedef unsigned short u16;
typedef __attribute__((ext_vector_type(8))) _Float16 half8;  // 8 f16 (4 VGPRs)
typedef __attribute__((ext_vector_type(16))) float f32x16;   // 32x32 MFMA acc

#define ZPLANE2 4194304   // 32768*128 (u16 elems per z plane)

// async global->LDS DMA, 16B/lane; LDS dest = wave-uniform base + lane*16.
__device__ __forceinline__ void gload16u(const u16* g, u16* l) {
    __builtin_amdgcn_global_load_lds((const AS1 void*)g, (AS3 void*)l, 16, 0, 0);
}

// ---------------- prep: 2-level fp16 split --------------------------------------
// z  = zh + zm + r (fp16 RNE twice, residual subtracts exact)  -> row-major planes
// e' = 2048*e = eh + em + r' -> e2p: MFMA-B-fragment-packed layout
//   e2p[strip n/32][j k/16][lv][lane (h=k8-half)*32 + (n&31)][slot k&7]
// so one wave B-frag load = one coalesced global_load_dwordx4 (1KB).
__global__ __launch_bounds__(256) void prep_kernel(const float* __restrict__ z,
                                                   const float* __restrict__ emb,
                                                   u16* __restrict__ z2,
                                                   u16* __restrict__ e2p) {
    const int ZQ = 1048576, EQ = 65536;            // float4 group counts
    int i = blockIdx.x * 256 + threadIdx.x;
    if (i >= ZQ + EQ) return;
    const bool isz = (i < ZQ);
    const float4 v = isz ? reinterpret_cast<const float4*>(z)[i]
                         : reinterpret_cast<const float4*>(emb)[i - ZQ];
    const float sc = isz ? 1.0f : 2048.0f;         // exact scaling
    float fv[4] = {v.x * sc, v.y * sc, v.z * sc, v.w * sc};
    u16 hs[4], ms[4];
    #pragma unroll
    for (int j = 0; j < 4; j++) {
        __half hh = __float2half_rn(fv[j]);
        float fh = __half2float(hh);
        float r = fv[j] - fh;                      // exact (Sterbenz / zero cases)
        __half hm = __float2half_rn(r);
        hs[j] = __half_as_ushort(hh);
        ms[j] = __half_as_ushort(hm);
    }
    if (isz) {
        size_t off = (size_t)i * 4;
        reinterpret_cast<ushort4*>(z2 + off)[0] = make_ushort4(hs[0], hs[1], hs[2], hs[3]);
        reinterpret_cast<ushort4*>(z2 + (size_t)ZPLANE2 + off)[0] = make_ushort4(ms[0], ms[1], ms[2], ms[3]);
    } else {
        int e = i - ZQ;                 // float4 index into emb [n][k]
        int n = e >> 5;                 // 32 groups per 128-k row
        int kb = (e & 31) * 4;          // k base (4 consecutive k, same half8)
        int strip = n >> 5, r32n = n & 31;
        int jj = kb >> 4, hh2 = (kb >> 3) & 1, slot = kb & 7;
        size_t base = ((size_t)(strip * 8 + jj) * 2) * 512
                    + (size_t)(hh2 * 32 + r32n) * 8 + slot;
        reinterpret_cast<ushort4*>(e2p + base)[0]       = make_ushort4(hs[0], hs[1], hs[2], hs[3]);
        reinterpret_cast<ushort4*>(e2p + base + 512)[0] = make_ushort4(ms[0], ms[1], ms[2], ms[3]);
    }
}

// ---------------- zsums: per-row ||z||^2, bitwise identical to rounds 5-10 --------
__global__ __launch_bounds__(256) void zsum_kernel(const float* __restrict__ z,
                                                   float* __restrict__ zsums) {
    __shared__ float zsh[128 * 128];
    const int tid = threadIdx.x;
    const int m0 = blockIdx.x * 128;
    for (int i = tid; i < 4096; i += 256) {
        int r = i >> 5, cc = i & 31;
        float4 v = reinterpret_cast<const float4*>(z + (size_t)(m0 + r) * EDIM)[cc];
        *reinterpret_cast<float4*>(&zsh[r * 128 + ((cc ^ ((r >> 3) & 7)) << 2)]) = v;
    }
    __syncthreads();
    if (tid < 128) {
        const float* zr = &zsh[tid * 128];
        const int key = (tid >> 3) & 7;
        float s = 0.0f;
        for (int cc = 0; cc < 32; cc++) {          // k-ascending (proven order)
            float4 v = *reinterpret_cast<const float4*>(zr + ((cc ^ key) << 2));
            s += v.x * v.x;
            s += v.y * v.y;
            s += v.z * v.z;
            s += v.w * v.w;
        }
        zsums[m0 + tid] = s;
    }
}

// ---------------- eq = ||e_n||^2, and zero the histogram (proven) ----------------
__global__ void eq_kernel(const float* __restrict__ emb, float* __restrict__ eq,
                          int* __restrict__ hist) {
    int n = blockIdx.x;
    int lane = threadIdx.x;
    float v0 = emb[(size_t)n * EDIM + lane];
    float v1 = emb[(size_t)n * EDIM + 64 + lane];
    float s = v0 * v0 + v1 * v1;
    #pragma unroll
    for (int off = 32; off >= 1; off >>= 1) s += __shfl_down(s, off);
    if (lane == 0) { eq[n] = s; hist[n] = 0; }
}

// ---------------- MFMA argmin: barrier-free main loop ----------------------------
// Same math as rounds 9-10 (bit-identical MFMA sequence & epilogue). Changes:
//  - B-frags loaded straight global->reg from e2p (coalesced dwordx4, L2-resident
//    1MB) -- no es staging, no per-window barriers.
//  - zs (A, 32KB) DMA'd once, read-only afterwards: the ONLY barriers are the
//    prologue and the final cand reduction. 8 waves/CU run free (2 blocks/CU).
// zs: [lv2][kchunk16][row64][8] u16; A-read = 32 rows x 16B contiguous (no conflict).
template<int WE>
__global__ __launch_bounds__(256, 2) void argmin_mfma_kernel(
    const u16* __restrict__ z2, const u16* __restrict__ e2p,
    const float* __restrict__ zsums, const float* __restrict__ eq,
    int* __restrict__ out_idx, float* __restrict__ out, int* __restrict__ hist)
{
    __shared__ __align__(16) u16 zs[16384];     // 32 KB
    __shared__ float zsl[64];
    __shared__ float cand_v[256];
    __shared__ int   cand_i[256];

    const int tid = threadIdx.x;
    const int w = tid >> 6, l = tid & 63;
    const int wn = w;                   // col quarter within the 128-col tt tile
    const int h = l >> 5, r32 = l & 31;
    const int m0 = blockIdx.x * 64;

    // prologue: DMA zs (2 levels, full K) -- 8 gloads/thread
    #pragma unroll
    for (int jj = 0; jj < 8; jj++) {
        int s0 = jj * 256 + w * 64;              // wave-uniform slot base
        int s = s0 + l;
        int lv = s >> 10, kc = (s >> 6) & 15, row = s & 63;
        gload16u(z2 + (size_t)lv * ZPLANE2 + ((size_t)(m0 + row) << 7) + kc * 8,
                 zs + s0 * 8);
    }
    if (tid < 64) zsl[tid] = zsums[m0 + tid];
    __syncthreads();    // drains vmcnt: zs + zsl ready; last block-wide barrier
                        // until the cand reduction.

    float best[2][16];
    int   bidx[2][16];
    #pragma unroll
    for (int i2 = 0; i2 < 2; i2++)
        #pragma unroll
        for (int q = 0; q < 16; q++) { best[i2][q] = 3.4e38f; bidx[i2][q] = 0; }

    float2* me2 = reinterpret_cast<float2*>(out + O_MINENC + (size_t)m0 * NE);

    for (int tt = 0; tt < 16; tt++) {           // 16 t-tiles x 128 cols
        if constexpr (WE) {                     // zero-fill 4 rows of the stripe
            const float2 zz2 = make_float2(0.0f, 0.0f);
            #pragma unroll
            for (int j = 0; j < 16; j++)
                me2[tt * 4096 + j * 256 + tid] = zz2;
        }

        f32x16 am[2], ac[2];
        #pragma unroll
        for (int i2 = 0; i2 < 2; i2++)
            #pragma unroll
            for (int q = 0; q < 16; q++) { am[i2][q] = 0.0f; ac[i2][q] = 0.0f; }

        const int strip = tt * 4 + wn;
        const u16* bb = e2p + ((size_t)strip * 16) * 512 + (size_t)l * 8;

        #pragma unroll 4
        for (int j = 0; j < 8; j++) {           // K=16 per step, k ascending
            half8 b0 = *reinterpret_cast<const half8*>(bb + (size_t)(j * 2 + 0) * 512);
            half8 b1 = *reinterpret_cast<const half8*>(bb + (size_t)(j * 2 + 1) * 512);
            half8 a00 = *reinterpret_cast<const half8*>(zs + ((0 * 16 + j * 2 + h) * 64 + 0 * 32 + r32) * 8);
            half8 a01 = *reinterpret_cast<const half8*>(zs + ((1 * 16 + j * 2 + h) * 64 + 0 * 32 + r32) * 8);
            half8 a10 = *reinterpret_cast<const half8*>(zs + ((0 * 16 + j * 2 + h) * 64 + 1 * 32 + r32) * 8);
            half8 a11 = *reinterpret_cast<const half8*>(zs + ((1 * 16 + j * 2 + h) * 64 + 1 * 32 + r32) * 8);

            am[0] = __builtin_amdgcn_mfma_f32_32x32x16_f16(a00, b0, am[0], 0, 0, 0);
            ac[0] = __builtin_amdgcn_mfma_f32_32x32x16_f16(a00, b1, ac[0], 0, 0, 0);
            ac[0] = __builtin_amdgcn_mfma_f32_32x32x16_f16(a01, b0, ac[0], 0, 0, 0);
            am[1] = __builtin_amdgcn_mfma_f32_32x32x16_f16(a10, b0, am[1], 0, 0, 0);
            ac[1] = __builtin_amdgcn_mfma_f32_32x32x16_f16(a10, b1, ac[1], 0, 0, 0);
            ac[1] = __builtin_amdgcn_mfma_f32_32x32x16_f16(a11, b0, ac[1], 0, 0, 0);
        }

        // epilogue: online argmin update (n ascending across tt; strict <)
        const int n = tt * 128 + wn * 32 + r32;
        const float eqv = eq[n];
        #pragma unroll
        for (int i2 = 0; i2 < 2; i2++) {
            #pragma unroll
            for (int q = 0; q < 16; q++) {
                const int row = i2 * 32 + ((q & 3) + 8 * (q >> 2) + 4 * h);
                float zse = zsl[row] + eqv;              // fp32 round at ~128 scale
                float dotp = am[i2][q] + ac[i2][q];      // one round
                float val = zse - dotp * 0.0009765625f;  // *2^-10 exact; one round
                if (val < best[i2][q]) { best[i2][q] = val; bidx[i2][q] = n; }
            }
        }
    }

    // reduce over the 32 col-lanes (offs <32 stay within each half)
    #pragma unroll
    for (int off = 16; off >= 1; off >>= 1) {
        #pragma unroll
        for (int i2 = 0; i2 < 2; i2++)
            #pragma unroll
            for (int q = 0; q < 16; q++) {
                float ov = __shfl_xor(best[i2][q], off);
                int   oi = __shfl_xor(bidx[i2][q], off);
                if (ov < best[i2][q] || (ov == best[i2][q] && oi < bidx[i2][q])) {
                    best[i2][q] = ov; bidx[i2][q] = oi;
                }
            }
    }
    if (r32 == 0) {            // lanes 0 and 32 per wave
        #pragma unroll
        for (int i2 = 0; i2 < 2; i2++)
            #pragma unroll
            for (int q = 0; q < 16; q++) {
                int row = i2 * 32 + ((q & 3) + 8 * (q >> 2) + 4 * h);
                cand_v[row * 4 + wn] = best[i2][q];
                cand_i[row * 4 + wn] = bidx[i2][q];
            }
    }
    __syncthreads();           // cand final; all zero-stores drained (vmcnt 0)
    if (tid < 64) {            // final: 4 wn-candidates; tie -> lower idx
        float bv = cand_v[tid * 4 + 0];
        int   bi = cand_i[tid * 4 + 0];
        #pragma unroll
        for (int j = 1; j < 4; j++) {
            float v = cand_v[tid * 4 + j];
            int   ii = cand_i[tid * 4 + j];
            if (v < bv || (v == bv && ii < bi)) { bv = v; bi = ii; }
        }
        out_idx[m0 + tid] = bi;
        out[O_IDX + m0 + tid] = (float)bi;
        atomicAdd(&hist[bi], 1);
        if constexpr (WE)
            out[O_MINENC + (size_t)(m0 + tid) * NE + bi] = 1.0f;
    }
}

// ---------------- min_encodings one-hot fill (fallback path only) ----------------
__global__ __launch_bounds__(256) void minenc_kernel(const int* __restrict__ idx,
                                                     float* __restrict__ out) {
    size_t i = (size_t)blockIdx.x * blockDim.x + threadIdx.x;
    const size_t total = (size_t)M_ROWS * (NE / 2);
    const size_t stride = (size_t)gridDim.x * blockDim.x;
    for (; i < total; i += stride) {
        int row = (int)(i >> 10);
        int col = (int)(i & 1023) << 1;
        int id = idx[row];
        float2 v;
        v.x = (col == id) ? 1.0f : 0.0f;
        v.y = (col + 1 == id) ? 1.0f : 0.0f;
        reinterpret_cast<float2*>(out)[i] = v;
    }
}

// ---------------- gather z_q, write z_q_st, loss partials ------------------------
__global__ __launch_bounds__(256) void gather_kernel(const float* __restrict__ z,
                                                     const float* __restrict__ emb,
                                                     const int* __restrict__ idx,
                                                     float* __restrict__ out,
                                                     float* __restrict__ partial) {
    __shared__ float red[256];
    const int tid = threadIdx.x;
    const int rl = tid >> 4;
    const int sub = tid & 15;
    const int row = blockIdx.x * 16 + rl;
    const int id = idx[row];

    const float* zr = z + (size_t)row * EDIM + sub * 8;
    const float* er = emb + (size_t)id * EDIM + sub * 8;
    float* outr = out + O_ZQ + (size_t)row * EDIM + sub * 8;

    float4 z0 = reinterpret_cast<const float4*>(zr)[0];
    float4 z1 = reinterpret_cast<const float4*>(zr)[1];
    float4 e0 = reinterpret_cast<const float4*>(er)[0];
    float4 e1 = reinterpret_cast<const float4*>(er)[1];

    float zz[8] = {z0.x, z0.y, z0.z, z0.w, z1.x, z1.y, z1.z, z1.w};
    float ee[8] = {e0.x, e0.y, e0.z, e0.w, e1.x, e1.y, e1.z, e1.w};
    float s = 0.0f;
    #pragma unroll
    for (int j = 0; j < 8; j++) {
        float d = ee[j] - zz[j];
        outr[j] = zz[j] + d;      // match reference's z + (z_q - z) rounding
        s += d * d;
    }
    red[tid] = s;
    __syncthreads();
    #pragma unroll
    for (int o = 128; o >= 1; o >>= 1) {
        if (tid < o) red[tid] += red[tid + o];
        __syncthreads();
    }
    if (tid == 0) partial[blockIdx.x] = red[0];
}

// ---------------- finalize: loss + perplexity (proven) ----------------
__global__ __launch_bounds__(256) void finalize_kernel(const float* __restrict__ partial,
                                                       const int* __restrict__ hist,
                                                       float* __restrict__ out) {
    __shared__ float red[256];
    const int tid = threadIdx.x;
    float s = 0.0f;
    for (int i = 0; i < 8; i++) s += partial[tid * 8 + i];
    red[tid] = s;
    __syncthreads();
    #pragma unroll
    for (int o = 128; o >= 1; o >>= 1) {
        if (tid < o) red[tid] += red[tid + o];
        __syncthreads();
    }
    if (tid == 0) out[O_LOSS] = 1.25f * red[0] / (float)((size_t)M_ROWS * EDIM);
    __syncthreads();

    float h = 0.0f;
    for (int i = 0; i < 8; i++) {
        float p = (float)hist[tid * 8 + i] * (1.0f / (float)M_ROWS);
        h += p * logf(p + 1e-10f);
    }
    red[tid] = h;
    __syncthreads();
    #pragma unroll
    for (int o = 128; o >= 1; o >>= 1) {
        if (tid < o) red[tid] += red[tid + o];
        __syncthreads();
    }
    if (tid == 0) out[O_PERP] = expf(-red[0]);
}

extern "C" void kernel_launch(void* const* d_in, const int* in_sizes, int n_in,
                              void* d_out, int out_size, void* d_ws, size_t ws_size,
                              hipStream_t stream) {
    const float* z   = (const float*)d_in[0];
    const float* emb = (const float*)d_in[1];
    float* out = (float*)d_out;

    char* ws = (char*)d_ws;
    float* eq    = (float*)ws;                    // 2048 f32
    int*   idx   = (int*)(ws + 8192);             // 32768 i32
    int*   hist  = (int*)(ws + 139264);           // 2048 i32
    float* part  = (float*)(ws + 147456);         // 2048 f32
    float* zsums = (float*)(ws + 155648);         // 32768 f32

    const bool big_ws = (ws_size >= (size_t)(40u << 20));   // fixed per session
    u16 *Z2, *E2P;
    if (big_ws) {                                 // planes + packed B in scratch
        Z2  = (u16*)(ws + (4u << 20));            // 16 MB (2 planes)
        E2P = (u16*)(ws + (24u << 20));           // 1 MB packed B-frags
    } else {                                      // fallback: use minenc region,
        Z2  = (u16*)(out + O_MINENC + 2);         // minenc kernel rewrites after
        E2P = Z2 + 2 * (size_t)ZPLANE2;
    }

    prep_kernel<<<4352, 256, 0, stream>>>(z, emb, Z2, E2P);
    zsum_kernel<<<256, 256, 0, stream>>>(z, zsums);
    eq_kernel<<<NE, 64, 0, stream>>>(emb, eq, hist);
    if (big_ws) {
        argmin_mfma_kernel<1><<<512, 256, 0, stream>>>(Z2, E2P, zsums, eq, idx, out, hist);
    } else {
        argmin_mfma_kernel<0><<<512, 256, 0, stream>>>(Z2, E2P, zsums, eq, idx, out, hist);
        minenc_kernel<<<8192, 256, 0, stream>>>(idx, out + O_MINENC);
    }
    gather_kernel<<<M_ROWS / 16, 256, 0, stream>>>(z, emb, idx, out, part);
    finalize_kernel<<<1, 256, 0, stream>>>(part, hist, out);
}